// Round 11
// baseline (1026.796 us; speedup 1.0000x reference)
//
#include <hip/hip_runtime.h>
#include <hip/hip_bf16.h>

#define NN 100000
#define NE 1600000
#define NCLS 101
#define EPS_BN 1e-5f
#define NINF (-__builtin_inff())
#define NBUCK 196      // ceil(NN/512)
#define BCAP 12288     // max edges/bucket (mean 8163, sd ~90)
#define G128B 782      // ceil(NN/128)
#define G192B 521      // ceil(NN/192)
#define CHUNK 2048     // edges per binning block

__device__ __forceinline__ int rl_i(int v, int j) {
    return __builtin_amdgcn_readlane(v, j);
}
__device__ __forceinline__ float rl_f(float v, int j) {
    return __int_as_float(__builtin_amdgcn_readlane(__float_as_int(v), j));
}
__device__ __forceinline__ float b2f(unsigned short u) {
    return __uint_as_float(((unsigned)u) << 16);
}

// ============================================================================
// CSR build, bucketed with block-level binning (R9, unchanged).
// ============================================================================
__global__ __launch_bounds__(256) void bucket_k(const int* __restrict__ src,
                                                const int* __restrict__ dst,
                                                int* __restrict__ bcnt16,
                                                int* __restrict__ bstore) {
    __shared__ int vals[CHUNK];
    __shared__ int sval[CHUNK];
    __shared__ unsigned char bks[CHUNK];
    __shared__ unsigned char sbk[CHUNK];
    __shared__ int hist[256];
    __shared__ int scn[256];
    __shared__ int loff[256];
    __shared__ int cur[256];
    __shared__ int gshift[256];
    int e0 = blockIdx.x * CHUNK;
    int cnt = NE - e0;
    if (cnt > CHUNK) cnt = CHUNK;
    int t = threadIdx.x;
    hist[t] = 0;
    __syncthreads();
    for (int i = t; i < cnt; i += 256) {
        int d = dst[e0 + i], s = src[e0 + i];
        int b = d >> 9;
        vals[i] = ((d & 511) << 17) | s;
        bks[i] = (unsigned char)b;
        atomicAdd(&hist[b], 1);
    }
    __syncthreads();
    int v = hist[t];
    scn[t] = v;
    __syncthreads();
    for (int off = 1; off < 256; off <<= 1) {
        int u = (t >= off) ? scn[t - off] : 0;
        __syncthreads();
        scn[t] += u;
        __syncthreads();
    }
    loff[t] = scn[t] - v;
    cur[t] = scn[t] - v;
    if (t < NBUCK) {
        int base = (v > 0) ? atomicAdd(&bcnt16[t * 16], v) : 0;
        gshift[t] = base - loff[t];
    }
    __syncthreads();
    for (int i = t; i < cnt; i += 256) {
        int b = bks[i];
        int p = atomicAdd(&cur[b], 1);
        sval[p] = vals[i];
        sbk[p] = (unsigned char)b;
    }
    __syncthreads();
    for (int i = t; i < cnt; i += 256) {
        int b = sbk[i];
        int q = gshift[b] + i;
        if (q < BCAP) bstore[(size_t)b * BCAP + q] = sval[i];
    }
}

__global__ __launch_bounds__(256) void bscan_k(const int* __restrict__ bcnt16,
                                               int* __restrict__ bbase) {
    __shared__ int sh[256];
    int t = threadIdx.x;
    int v = (t < NBUCK) ? bcnt16[t * 16] : 0;
    sh[t] = v;
    __syncthreads();
    for (int off = 1; off < 256; off <<= 1) {
        int u = (t >= off) ? sh[t - off] : 0;
        __syncthreads();
        sh[t] += u;
        __syncthreads();
    }
    if (t < NBUCK) bbase[t] = sh[t] - v;
}

__global__ __launch_bounds__(512) void b2csr_k(const int* __restrict__ bcnt16,
                                               const int* __restrict__ bbase,
                                               const int* __restrict__ bstore,
                                               int* __restrict__ rs,
                                               int* __restrict__ csrc) {
    __shared__ int hist[512];
    __shared__ int scn[512];
    __shared__ int cur[512];
    int b = blockIdx.x;
    int t = threadIdx.x;
    int cnt = bcnt16[b * 16];
    if (cnt > BCAP) cnt = BCAP;
    int gbase = bbase[b];
    const int* bs = bstore + (size_t)b * BCAP;
    hist[t] = 0;
    __syncthreads();
    for (int i = t; i < cnt; i += 512) atomicAdd(&hist[bs[i] >> 17], 1);
    __syncthreads();
    int v = hist[t];
    scn[t] = v;
    __syncthreads();
    for (int off = 1; off < 512; off <<= 1) {
        int u = (t >= off) ? scn[t - off] : 0;
        __syncthreads();
        scn[t] += u;
        __syncthreads();
    }
    int ex = scn[t] - v;
    cur[t] = ex;
    int node = b * 512 + t;
    if (node < NN) rs[node] = gbase + ex;
    if (b == 0 && t == 0) rs[NN] = NE;
    __syncthreads();
    for (int i = t; i < cnt; i += 512) {
        int e = bs[i];
        int p = atomicAdd(&cur[e >> 17], 1);
        csrc[gbase + p] = e & 0x1FFFF;
    }
}

__global__ __launch_bounds__(256) void pos2_k(const float* __restrict__ pos,
                                              float2* __restrict__ pos2) {
    int n = blockIdx.x * 256 + threadIdx.x;
    if (n < NN) pos2[n] = make_float2(pos[n * 3], pos[n * 3 + 1]);
}

// ============================================================================
// One-shot weight packing (unchanged).
// ============================================================================
__global__ __launch_bounds__(256) void pack_all_k(
    const float* __restrict__ wl_stem, const float* __restrict__ wg_stem,
    const float* __restrict__ wl_c1, const float* __restrict__ bl_c1,
    const float* __restrict__ wl_c2, const float* __restrict__ bl_c2,
    const float* __restrict__ wg_c1, const float* __restrict__ wg_c2,
    const float* __restrict__ wl_reg, const float* __restrict__ wl_obj,
    const float* __restrict__ bl_reg, const float* __restrict__ bl_obj,
    const float* __restrict__ wl_cls, const float* __restrict__ wg_cls,
    float* __restrict__ wT_sp, float* __restrict__ wT_sg,
    float* __restrict__ wT_12, float* __restrict__ wT_g1,
    float* __restrict__ wT_g2, float* __restrict__ wT_ro,
    float* __restrict__ wT_cp, float* __restrict__ wT_cg,
    float* __restrict__ bAB, float* __restrict__ wro, float* __restrict__ bro) {
    int u = blockIdx.x * 256 + threadIdx.x;
    if (u < 4096) { int j = u >> 6, c = u & 63; wT_sp[u] = wl_stem[c * 66 + j]; return; }
    u -= 4096;
    if (u < 4096) { int j = u >> 6, c = u & 63; wT_sg[u] = wg_stem[c * 64 + j]; return; }
    u -= 4096;
    if (u < 8192) { int j = u >> 7, c = u & 127; int k = c >> 1;
        wT_12[u] = ((c & 1) ? wl_c2 : wl_c1)[k * 66 + j]; return; }
    u -= 8192;
    if (u < 4096) { int j = u >> 6, c = u & 63; wT_g1[u] = wg_c1[c * 64 + j]; return; }
    u -= 4096;
    if (u < 4096) { int j = u >> 6, c = u & 63; wT_g2[u] = wg_c2[c * 64 + j]; return; }
    u -= 4096;
    if (u < 1024) { int j = u >> 4, c = u & 15;
        wT_ro[u] = (c < 4) ? wl_reg[c * 66 + j] : ((c == 4) ? wl_obj[j] : 0.f); return; }
    u -= 1024;
    if (u < 7168) { int j = u / 112, c = u - j * 112;
        wT_cp[u] = (c < NCLS) ? wl_cls[c * 66 + j] : 0.f; return; }
    u -= 7168;
    if (u < 11312) { int j = u / 112, c = u - j * 112;
        wT_cg[u] = (c < NCLS) ? wg_cls[c * NCLS + j] : 0.f; return; }
    u -= 11312;
    if (u < 128) { bAB[u] = (u & 1) ? bl_c2[u >> 1] : bl_c1[u >> 1]; return; }
    u -= 128;
    if (u < 330) { int cc = u / 66, j = u - cc * 66;
        wro[u] = (cc < 4) ? wl_reg[u] : wl_obj[j]; return; }
    u -= 330;
    if (u < 5) bro[u] = (u < 4) ? bl_reg[u] : bl_obj[0];
}

// ============================================================================
// Node-side GEMM. BNF: fused BN+ReLU on input staging. STOUT: per-block
// sum/sumsq partials (no atomics). BOUT: bf16 output. MT = nodes/block
// (RM = MT/64 nodes/thread) amortizes the wave-uniform wsh broadcasts.
// ============================================================================
template <int COUT, int CPW, int K, int IS, int OS, int MT, bool BNF, bool STOUT,
          bool BOUT>
__global__ __launch_bounds__(256) void gemm_k(const float* __restrict__ in,
                                              const float* __restrict__ wT,
                                              const float* __restrict__ bias,
                                              const float* __restrict__ st,
                                              float* __restrict__ stpart,
                                              float* __restrict__ out) {
    constexpr int CP = 4 * CPW;
    constexpr int RM = MT / 64;
    constexpr int XR = MT + 1;
    __shared__ __align__(16) float xs[K * XR];
    __shared__ __align__(16) float wsh[K * CP];
    int base = blockIdx.x * MT;
    for (int p = threadIdx.x; p < K * CP / 4; p += 256)
        ((float4*)wsh)[p] = ((const float4*)wT)[p];
    for (int p = threadIdx.x; p < MT * K; p += 256) {
        int n = p / K, j = p - n * K;
        float v = (base + n < NN) ? in[(size_t)(base + n) * IS + j] : 0.f;
        if constexpr (BNF) v = fmaxf(fmaf(v, st[128 + j], st[192 + j]), 0.f);
        xs[j * XR + n] = v;
    }
    __syncthreads();
    int wid = __builtin_amdgcn_readfirstlane(threadIdx.x >> 6);
    int lane = threadIdx.x & 63;
    int c0 = wid * CPW;
    if (c0 >= COUT) return;     // after the only barrier -> safe
    float acc[RM][CPW];
#pragma unroll
    for (int k = 0; k < CPW; ++k) {
        float bv = (c0 + k < COUT) ? bias[c0 + k] : 0.f;
#pragma unroll
        for (int r = 0; r < RM; ++r) acc[r][k] = bv;
    }
    for (int j = 0; j < K; ++j) {
        float a[RM];
#pragma unroll
        for (int r = 0; r < RM; ++r) a[r] = xs[j * XR + 64 * r + lane];
#pragma unroll
        for (int q = 0; q < CPW / 4; ++q) {
            float4 wv = *(const float4*)&wsh[j * CP + c0 + 4 * q];
#pragma unroll
            for (int r = 0; r < RM; ++r) {
                acc[r][4 * q + 0] = fmaf(a[r], wv.x, acc[r][4 * q + 0]);
                acc[r][4 * q + 1] = fmaf(a[r], wv.y, acc[r][4 * q + 1]);
                acc[r][4 * q + 2] = fmaf(a[r], wv.z, acc[r][4 * q + 2]);
                acc[r][4 * q + 3] = fmaf(a[r], wv.w, acc[r][4 * q + 3]);
            }
        }
    }
#pragma unroll
    for (int r = 0; r < RM; ++r) {
        int node = base + 64 * r + lane;
        if (node < NN) {
#pragma unroll
            for (int k = 0; k < CPW; ++k) {
                if (c0 + k < COUT) {
                    if constexpr (BOUT) {
                        __hip_bfloat16* ob = (__hip_bfloat16*)out;
                        ob[(size_t)node * OS + c0 + k] = __float2bfloat16(acc[r][k]);
                    } else {
                        out[(size_t)node * OS + c0 + k] = acc[r][k];
                    }
                }
            }
        }
    }
    if constexpr (STOUT) {
        float* sp = stpart + (size_t)blockIdx.x * 128;
#pragma unroll
        for (int k = 0; k < CPW; ++k) {
            if (c0 + k < COUT) {
                float s = 0.f, q = 0.f;
#pragma unroll
                for (int r = 0; r < RM; ++r) {
                    float v = (base + 64 * r + lane < NN) ? acc[r][k] : 0.f;
                    s += v;
                    q = fmaf(v, v, q);
                }
#pragma unroll
                for (int off = 1; off < 64; off <<= 1) {
                    s += __shfl_xor(s, off, 64);
                    q += __shfl_xor(q, off, 64);
                }
                if (lane == 0) {
                    sp[c0 + k] = s;
                    sp[64 + c0 + k] = q;
                }
            }
        }
    }
}

// reduce per-block partials -> BN scale/shift. One block, 256 threads.
__global__ __launch_bounds__(256) void bnpar_k(const float* __restrict__ stpart,
                                               const float* __restrict__ g,
                                               const float* __restrict__ b,
                                               float* __restrict__ st, int nparts) {
    __shared__ float sS[4][64], sQ[4][64];
    int c = threadIdx.x & 63;
    int part = threadIdx.x >> 6;
    float s = 0.f, q = 0.f;
    for (int i = part; i < nparts; i += 4) {
        s += stpart[(size_t)i * 128 + c];
        q += stpart[(size_t)i * 128 + 64 + c];
    }
    sS[part][c] = s;
    sQ[part][c] = q;
    __syncthreads();
    if (part == 0) {
        s = sS[0][c] + sS[1][c] + sS[2][c] + sS[3][c];
        q = sQ[0][c] + sQ[1][c] + sQ[2][c] + sQ[3][c];
        float mu = s * (1.0f / NN);
        float var = q * (1.0f / NN) - mu * mu;
        float sc = g[c] * rsqrtf(var + EPS_BN);
        st[128 + c] = sc;
        st[192 + c] = b[c] - mu * sc;
    }
}

// ============================================================================
// Edge segment-max over CSR, bf16 payloads (R10, unchanged).
// ============================================================================
__global__ __launch_bounds__(256) void edge1_k(const unsigned short* __restrict__ y,  // bf16, stride 64
                                               const float2* __restrict__ pos2,
                                               const int* __restrict__ rs,
                                               const int* __restrict__ csrc,
                                               const float* __restrict__ wl,  // (64,66)
                                               float* __restrict__ agg) {
    int wid = __builtin_amdgcn_readfirstlane(threadIdx.x >> 6);
    int lane = threadIdx.x & 63;
    int node = blockIdx.x * 4 + wid;
    if (node >= NN) return;
    float wp0 = wl[lane * 66 + 64], wp1 = wl[lane * 66 + 65];
    float2 pd = pos2[node];
    int i0 = rs[node], i1 = rs[node + 1];
    float acc = NINF;
    for (int ib = i0; ib < i1; ib += 64) {
        int m = i1 - ib;
        if (m > 64) m = 64;
        int t = ib + lane;
        int idx = (t < i1) ? csrc[t] : 0;
        float2 pp = pos2[idx];
        float ppx = pp.x, ppy = pp.y;
        int j = 0;
        for (; j + 8 <= m; j += 8) {
            float v[8];
#pragma unroll
            for (int q = 0; q < 8; ++q)
                v[q] = b2f(y[(size_t)rl_i(idx, j + q) * 64 + lane]);
#pragma unroll
            for (int q = 0; q < 8; ++q) {
                float dx = rl_f(ppx, j + q) - pd.x, dy = rl_f(ppy, j + q) - pd.y;
                acc = fmaxf(acc, fmaf(dy, wp1, fmaf(dx, wp0, v[q])));
            }
        }
        for (; j < m; ++j) {
            float v = b2f(y[(size_t)rl_i(idx, j) * 64 + lane]);
            acc = fmaxf(acc, fmaf(rl_f(ppy, j) - pd.y, wp1,
                                  fmaf(rl_f(ppx, j) - pd.x, wp0, v)));
        }
    }
    agg[(size_t)node * 64 + lane] = fmaxf(acc, 0.0f);
}

// y12: bf16 [n][64]{c1,c2} pairs -> one uint per lane
__global__ __launch_bounds__(256) void edge2_k(const unsigned* __restrict__ y12,
                                               const float2* __restrict__ pos2,
                                               const int* __restrict__ rs,
                                               const int* __restrict__ csrc,
                                               const float* __restrict__ wlA,
                                               const float* __restrict__ wlB,
                                               float* __restrict__ a1,
                                               float* __restrict__ a2) {
    int wid = __builtin_amdgcn_readfirstlane(threadIdx.x >> 6);
    int lane = threadIdx.x & 63;
    int node = blockIdx.x * 4 + wid;
    if (node >= NN) return;
    float wa0 = wlA[lane * 66 + 64], wa1 = wlA[lane * 66 + 65];
    float wb0 = wlB[lane * 66 + 64], wb1 = wlB[lane * 66 + 65];
    float2 pd = pos2[node];
    int i0 = rs[node], i1 = rs[node + 1];
    float accA = NINF, accB = NINF;
    for (int ib = i0; ib < i1; ib += 64) {
        int m = i1 - ib;
        if (m > 64) m = 64;
        int t = ib + lane;
        int idx = (t < i1) ? csrc[t] : 0;
        float2 pp = pos2[idx];
        float ppx = pp.x, ppy = pp.y;
        int j = 0;
        for (; j + 8 <= m; j += 8) {
            unsigned w[8];
#pragma unroll
            for (int q = 0; q < 8; ++q)
                w[q] = y12[(size_t)rl_i(idx, j + q) * 64 + lane];
#pragma unroll
            for (int q = 0; q < 8; ++q) {
                float dx = rl_f(ppx, j + q) - pd.x, dy = rl_f(ppy, j + q) - pd.y;
                accA = fmaxf(accA, fmaf(dy, wa1, fmaf(dx, wa0,
                                        b2f((unsigned short)w[q]))));
                accB = fmaxf(accB, fmaf(dy, wb1, fmaf(dx, wb0,
                                        b2f((unsigned short)(w[q] >> 16)))));
            }
        }
        for (; j < m; ++j) {
            unsigned w = y12[(size_t)rl_i(idx, j) * 64 + lane];
            float dx = rl_f(ppx, j) - pd.x, dy = rl_f(ppy, j) - pd.y;
            accA = fmaxf(accA, fmaf(dy, wa1, fmaf(dx, wa0, b2f((unsigned short)w))));
            accB = fmaxf(accB, fmaf(dy, wb1, fmaf(dx, wb0,
                                    b2f((unsigned short)(w >> 16)))));
        }
    }
    a1[(size_t)node * 64 + lane] = fmaxf(accA, 0.0f);
    a2[(size_t)node * 64 + lane] = fmaxf(accB, 0.0f);
}

// cls: wave per node, lane covers channels {lane, lane+64 (clamped)}
__global__ __launch_bounds__(256) void edge_cls_k(const unsigned short* __restrict__ y,  // bf16, stride 104
                                                  const float2* __restrict__ pos2,
                                                  const int* __restrict__ rs,
                                                  const int* __restrict__ csrc,
                                                  const float* __restrict__ wl,  // (101,66)
                                                  float* __restrict__ agg) {     // fp32, stride 104
    int wid = __builtin_amdgcn_readfirstlane(threadIdx.x >> 6);
    int lane = threadIdx.x & 63;
    int node = blockIdx.x * 4 + wid;
    if (node >= NN) return;
    int chi = (lane + 64 < NCLS) ? (lane + 64) : (NCLS - 1);
    float wa0 = wl[lane * 66 + 64], wa1 = wl[lane * 66 + 65];
    float wb0 = wl[chi * 66 + 64], wb1 = wl[chi * 66 + 65];
    float2 pd = pos2[node];
    int i0 = rs[node], i1 = rs[node + 1];
    float accA = NINF, accB = NINF;
    for (int ib = i0; ib < i1; ib += 64) {
        int m = i1 - ib;
        if (m > 64) m = 64;
        int t = ib + lane;
        int idx = (t < i1) ? csrc[t] : 0;
        float2 pp = pos2[idx];
        float ppx = pp.x, ppy = pp.y;
        int j = 0;
        for (; j + 4 <= m; j += 4) {
            float va[4], vb[4];
#pragma unroll
            for (int q = 0; q < 4; ++q) {
                size_t row = (size_t)rl_i(idx, j + q) * 104;
                va[q] = b2f(y[row + lane]);
                vb[q] = b2f(y[row + chi]);
            }
#pragma unroll
            for (int q = 0; q < 4; ++q) {
                float dx = rl_f(ppx, j + q) - pd.x, dy = rl_f(ppy, j + q) - pd.y;
                accA = fmaxf(accA, fmaf(dy, wa1, fmaf(dx, wa0, va[q])));
                accB = fmaxf(accB, fmaf(dy, wb1, fmaf(dx, wb0, vb[q])));
            }
        }
        for (; j < m; ++j) {
            size_t row = (size_t)rl_i(idx, j) * 104;
            float va = b2f(y[row + lane]);
            float vb = b2f(y[row + chi]);
            float dx = rl_f(ppx, j) - pd.x, dy = rl_f(ppy, j) - pd.y;
            accA = fmaxf(accA, fmaf(dy, wa1, fmaf(dx, wa0, va)));
            accB = fmaxf(accB, fmaf(dy, wb1, fmaf(dx, wb0, vb)));
        }
    }
    agg[(size_t)node * 104 + lane] = fmaxf(accA, 0.0f);
    if (lane + 64 < NCLS) agg[(size_t)node * 104 + 64 + lane] = fmaxf(accB, 0.0f);
}

// reg+obj: 5 bf16 channels packed stride 8; wave = 8 edge-slots x 8 ch-slots
__global__ __launch_bounds__(256) void edge_ro_k(const unsigned short* __restrict__ y,  // bf16, stride 8
                                                 const float2* __restrict__ pos2,
                                                 const int* __restrict__ rs,
                                                 const int* __restrict__ csrc,
                                                 const float* __restrict__ wro,  // (5,66)
                                                 float* __restrict__ aggr,
                                                 float* __restrict__ aggo) {
    int wid = __builtin_amdgcn_readfirstlane(threadIdx.x >> 6);
    int lane = threadIdx.x & 63;
    int node = blockIdx.x * 4 + wid;
    if (node >= NN) return;
    int k = lane >> 3, c = lane & 7;
    int cc = (c < 5) ? c : 4;
    float wp0 = wro[cc * 66 + 64], wp1 = wro[cc * 66 + 65];
    float2 pd = pos2[node];
    int i0 = rs[node], i1 = rs[node + 1];
    float acc = NINF;
    for (int i = i0 + k; i < i1; i += 8) {
        int s = csrc[i];
        float2 p = pos2[s];
        float v = b2f(y[(size_t)s * 8 + cc]);
        acc = fmaxf(acc, fmaf(p.y - pd.y, wp1, fmaf(p.x - pd.x, wp0, v)));
    }
    acc = fmaxf(acc, __shfl_xor(acc, 8, 64));
    acc = fmaxf(acc, __shfl_xor(acc, 16, 64));
    acc = fmaxf(acc, __shfl_xor(acc, 32, 64));
    acc = fmaxf(acc, 0.0f);
    if (lane < 5) {
        if (lane < 4) aggr[(size_t)node * 4 + lane] = acc;
        else          aggo[node] = acc;
    }
}

__global__ __launch_bounds__(256) void final_ro_k(const float* __restrict__ aggr,
                                                  const float* __restrict__ aggo,
                                                  const float* __restrict__ wgr,
                                                  const float* __restrict__ bgr,
                                                  const float* __restrict__ wgo,
                                                  const float* __restrict__ bgo,
                                                  float* __restrict__ out) {
    int n = blockIdx.x * 256 + threadIdx.x;
    if (n >= NN) return;
    float a0 = aggr[(size_t)n * 4 + 0], a1 = aggr[(size_t)n * 4 + 1];
    float a2 = aggr[(size_t)n * 4 + 2], a3 = aggr[(size_t)n * 4 + 3];
    float* reg = out + (size_t)NN * NCLS;
    float* obj = reg + (size_t)NN * 4;
#pragma unroll
    for (int k = 0; k < 4; ++k) {
        float acc = bgr[k];
        acc = fmaf(a0, wgr[k * 4 + 0], acc);
        acc = fmaf(a1, wgr[k * 4 + 1], acc);
        acc = fmaf(a2, wgr[k * 4 + 2], acc);
        acc = fmaf(a3, wgr[k * 4 + 3], acc);
        reg[(size_t)n * 4 + k] = acc;
    }
    obj[n] = fmaf(aggo[n], wgo[0], bgo[0]);
}

// ============================================================================
extern "C" void kernel_launch(void* const* d_in, const int* in_sizes, int n_in,
                              void* d_out, int out_size, void* d_ws, size_t ws_size,
                              hipStream_t stream) {
    const float* x   = (const float*)d_in[0];
    const float* pos = (const float*)d_in[1];
    const int* ei    = (const int*)d_in[2];
    const int* src = ei;
    const int* dst = ei + NE;
    const float* wl_stem = (const float*)d_in[3];
    const float* bl_stem = (const float*)d_in[4];
    const float* wg_stem = (const float*)d_in[5];
    const float* bg_stem = (const float*)d_in[6];
    const float* g_stem  = (const float*)d_in[7];
    const float* b_stem  = (const float*)d_in[8];
    const float* wl_c1 = (const float*)d_in[9];
    const float* bl_c1 = (const float*)d_in[10];
    const float* wg_c1 = (const float*)d_in[11];
    const float* bg_c1 = (const float*)d_in[12];
    const float* g_c1  = (const float*)d_in[13];
    const float* b_c1  = (const float*)d_in[14];
    const float* wl_c2 = (const float*)d_in[15];
    const float* bl_c2 = (const float*)d_in[16];
    const float* wg_c2 = (const float*)d_in[17];
    const float* bg_c2 = (const float*)d_in[18];
    const float* g_c2  = (const float*)d_in[19];
    const float* b_c2  = (const float*)d_in[20];
    const float* wl_reg = (const float*)d_in[21];
    const float* bl_reg = (const float*)d_in[22];
    const float* wg_reg = (const float*)d_in[23];
    const float* bg_reg = (const float*)d_in[24];
    const float* wl_cls = (const float*)d_in[25];
    const float* bl_cls = (const float*)d_in[26];
    const float* wg_cls = (const float*)d_in[27];
    const float* bg_cls = (const float*)d_in[28];
    const float* wl_obj = (const float*)d_in[29];
    const float* bl_obj = (const float*)d_in[30];
    const float* wg_obj = (const float*)d_in[31];
    const float* bg_obj = (const float*)d_in[32];

    float* ws = (float*)d_ws;
    // Arena: S0[N*128] | S1[N*64] | S2[N*64] | S3[N*64] | ints/smalls
    float* S0 = ws;
    float* S1 = S0 + (size_t)NN * 128;
    float* S2 = S1 + (size_t)NN * 64;
    float* S3 = S2 + (size_t)NN * 64;
    float* y12   = S0;       // bf16 [n][128]
    float* y_cls = S0;       // bf16 [n][104]
    float* aggc  = S1;       // fp32 N*104 spans S1+S2 (both dead by then)
    int*   bstore = (int*)S0;                     // NBUCK*BCAP ints
    int*   rs   = (int*)(S3 + (size_t)NN * 64);   // NN+1 (padded to 100016)
    int*   csrc = rs + 100016;                    // NE
    float* pos2 = (float*)(csrc + NE);            // NN float2
    float* y_ro = pos2 + (size_t)NN * 2;          // bf16 [n][8] (slot sized for fp32)
    float* aggr = y_ro + (size_t)NN * 8;          // NN*4
    float* aggo = aggr + (size_t)NN * 4;          // NN
    float* st   = aggo + NN;                      // 3*256 (params at [128..255])
    float* st0 = st, *st1 = st + 256, *st2 = st + 512;
    float* wro = st + 768;                        // 336
    float* bro = wro + 336;                       // 8
    int*   bcnt16 = (int*)(bro + 8);              // NBUCK*16 (line-padded)
    int*   bbase  = bcnt16 + NBUCK * 16;          // 256
    float* wT_sp = (float*)(bbase + 256);         // [64][64]
    float* wT_sg = wT_sp + 4096;
    float* wT_12 = wT_sg + 4096;                  // [64][128]
    float* wT_g1 = wT_12 + 8192;
    float* wT_g2 = wT_g1 + 4096;
    float* wT_ro = wT_g2 + 4096;                  // [64][16]
    float* wT_cp = wT_ro + 1024;                  // [64][112]
    float* wT_cg = wT_cp + 7168;                  // [101][112]
    float* bAB   = wT_cg + 11312;                 // 128
    float* stpart = bAB + 128;                    // G128B*128 partials (400 KB)

    hipMemsetAsync(bcnt16, 0, NBUCK * 16 * sizeof(int), stream);

    const int NB = (NN + 255) / 256;      // 391
    const int N4 = (NN + 3) / 4;          // 25000
    const int CB = (NE + CHUNK - 1) / CHUNK;  // 782 binning blocks

    // ---- packing + CSR build + pos2 ----
    pack_all_k<<<175, 256, 0, stream>>>(wl_stem, wg_stem, wl_c1, bl_c1, wl_c2,
                                        bl_c2, wg_c1, wg_c2, wl_reg, wl_obj,
                                        bl_reg, bl_obj, wl_cls, wg_cls,
                                        wT_sp, wT_sg, wT_12, wT_g1, wT_g2,
                                        wT_ro, wT_cp, wT_cg, bAB, wro, bro);
    pos2_k<<<NB, 256, 0, stream>>>(pos, (float2*)pos2);
    bucket_k<<<CB, 256, 0, stream>>>(src, dst, bcnt16, bstore);
    bscan_k<<<1, 256, 0, stream>>>(bcnt16, bbase);
    b2csr_k<<<NBUCK, 512, 0, stream>>>(bcnt16, bbase, bstore, rs, csrc);

    // ---- stem ----
    gemm_k<64, 16, 64, 64, 64, 192, false, false, true><<<G192B, 256, 0, stream>>>(
        x, wT_sp, bl_stem, nullptr, nullptr, S1);          // y_stem bf16 in S1
    edge1_k<<<N4, 256, 0, stream>>>((const unsigned short*)S1, (float2*)pos2, rs,
                                    csrc, wl_stem, S2);
    gemm_k<64, 16, 64, 64, 64, 192, false, true, false><<<G192B, 256, 0, stream>>>(
        S2, wT_sg, bg_stem, nullptr, stpart, S2);
    bnpar_k<<<1, 256, 0, stream>>>(stpart, g_stem, b_stem, st0, G192B);

    // ---- c1 + c2 (BN fused into packed projection, shared edge pass) ----
    gemm_k<128, 32, 64, 64, 128, 128, true, false, true><<<G128B, 256, 0, stream>>>(
        S2, wT_12, bAB, st0, nullptr, y12);                // y12 bf16
    edge2_k<<<N4, 256, 0, stream>>>((const unsigned*)y12, (float2*)pos2, rs, csrc,
                                    wl_c1, wl_c2, S1, S3);
    gemm_k<64, 16, 64, 64, 64, 192, false, true, false><<<G192B, 256, 0, stream>>>(
        S1, wT_g1, bg_c1, nullptr, stpart, S1);
    bnpar_k<<<1, 256, 0, stream>>>(stpart, g_c1, b_c1, st1, G192B);
    gemm_k<64, 16, 64, 64, 64, 192, false, true, false><<<G192B, 256, 0, stream>>>(
        S3, wT_g2, bg_c2, nullptr, stpart, S3);
    bnpar_k<<<1, 256, 0, stream>>>(stpart, g_c2, b_c2, st2, G192B);

    // ---- reg + obj heads (input x1 = BN(S1), fused) ----
    gemm_k<5, 4, 64, 64, 8, 192, true, false, true><<<G192B, 256, 0, stream>>>(
        S1, wT_ro, bro, st1, nullptr, y_ro);               // y_ro bf16
    edge_ro_k<<<N4, 256, 0, stream>>>((const unsigned short*)y_ro, (float2*)pos2,
                                      rs, csrc, wro, aggr, aggo);

    // ---- cls head (input x2 = BN(S3), fused) ----
    gemm_k<101, 28, 64, 64, 104, 128, true, false, true><<<G128B, 256, 0, stream>>>(
        S3, wT_cp, bl_cls, st2, nullptr, y_cls);           // y_cls bf16
    edge_cls_k<<<N4, 256, 0, stream>>>((const unsigned short*)y_cls, (float2*)pos2,
                                       rs, csrc, wl_cls, aggc);
    gemm_k<101, 28, 101, 104, 101, 128, false, false, false><<<G128B, 256, 0, stream>>>(
        aggc, wT_cg, bg_cls, nullptr, nullptr, (float*)d_out);
    final_ro_k<<<NB, 256, 0, stream>>>(aggr, aggo, wg_reg, bg_reg, wg_obj, bg_obj,
                                       (float*)d_out);
}

// Round 12
// 982.132 us; speedup vs baseline: 1.0455x; 1.0455x over previous
//
#include <hip/hip_runtime.h>
#include <hip/hip_bf16.h>

#define NN 100000
#define NE 1600000
#define NCLS 101
#define EPS_BN 1e-5f
#define NINF (-__builtin_inff())
#define NBUCK 196      // ceil(NN/512)
#define BCAP 12288     // max edges/bucket (mean 8163, sd ~90)
#define G128B 782      // ceil(NN/128)
#define G192B 521      // ceil(NN/192)
#define CHUNK 2048     // edges per binning block

__device__ __forceinline__ int rl_i(int v, int j) {
    return __builtin_amdgcn_readlane(v, j);
}
__device__ __forceinline__ float rl_f(float v, int j) {
    return __int_as_float(__builtin_amdgcn_readlane(__float_as_int(v), j));
}
__device__ __forceinline__ float b2f(unsigned short u) {
    return __uint_as_float(((unsigned)u) << 16);
}

// ============================================================================
// CSR build, bucketed with block-level binning (R9, unchanged).
// ============================================================================
__global__ __launch_bounds__(256) void bucket_k(const int* __restrict__ src,
                                                const int* __restrict__ dst,
                                                int* __restrict__ bcnt16,
                                                int* __restrict__ bstore) {
    __shared__ int vals[CHUNK];
    __shared__ int sval[CHUNK];
    __shared__ unsigned char bks[CHUNK];
    __shared__ unsigned char sbk[CHUNK];
    __shared__ int hist[256];
    __shared__ int scn[256];
    __shared__ int loff[256];
    __shared__ int cur[256];
    __shared__ int gshift[256];
    int e0 = blockIdx.x * CHUNK;
    int cnt = NE - e0;
    if (cnt > CHUNK) cnt = CHUNK;
    int t = threadIdx.x;
    hist[t] = 0;
    __syncthreads();
    for (int i = t; i < cnt; i += 256) {
        int d = dst[e0 + i], s = src[e0 + i];
        int b = d >> 9;
        vals[i] = ((d & 511) << 17) | s;
        bks[i] = (unsigned char)b;
        atomicAdd(&hist[b], 1);
    }
    __syncthreads();
    int v = hist[t];
    scn[t] = v;
    __syncthreads();
    for (int off = 1; off < 256; off <<= 1) {
        int u = (t >= off) ? scn[t - off] : 0;
        __syncthreads();
        scn[t] += u;
        __syncthreads();
    }
    loff[t] = scn[t] - v;
    cur[t] = scn[t] - v;
    if (t < NBUCK) {
        int base = (v > 0) ? atomicAdd(&bcnt16[t * 16], v) : 0;
        gshift[t] = base - loff[t];
    }
    __syncthreads();
    for (int i = t; i < cnt; i += 256) {
        int b = bks[i];
        int p = atomicAdd(&cur[b], 1);
        sval[p] = vals[i];
        sbk[p] = (unsigned char)b;
    }
    __syncthreads();
    for (int i = t; i < cnt; i += 256) {
        int b = sbk[i];
        int q = gshift[b] + i;
        if (q < BCAP) bstore[(size_t)b * BCAP + q] = sval[i];
    }
}

__global__ __launch_bounds__(256) void bscan_k(const int* __restrict__ bcnt16,
                                               int* __restrict__ bbase) {
    __shared__ int sh[256];
    int t = threadIdx.x;
    int v = (t < NBUCK) ? bcnt16[t * 16] : 0;
    sh[t] = v;
    __syncthreads();
    for (int off = 1; off < 256; off <<= 1) {
        int u = (t >= off) ? sh[t - off] : 0;
        __syncthreads();
        sh[t] += u;
        __syncthreads();
    }
    if (t < NBUCK) bbase[t] = sh[t] - v;
}

__global__ __launch_bounds__(512) void b2csr_k(const int* __restrict__ bcnt16,
                                               const int* __restrict__ bbase,
                                               const int* __restrict__ bstore,
                                               int* __restrict__ rs,
                                               int* __restrict__ csrc) {
    __shared__ int hist[512];
    __shared__ int scn[512];
    __shared__ int cur[512];
    int b = blockIdx.x;
    int t = threadIdx.x;
    int cnt = bcnt16[b * 16];
    if (cnt > BCAP) cnt = BCAP;
    int gbase = bbase[b];
    const int* bs = bstore + (size_t)b * BCAP;
    hist[t] = 0;
    __syncthreads();
    for (int i = t; i < cnt; i += 512) atomicAdd(&hist[bs[i] >> 17], 1);
    __syncthreads();
    int v = hist[t];
    scn[t] = v;
    __syncthreads();
    for (int off = 1; off < 512; off <<= 1) {
        int u = (t >= off) ? scn[t - off] : 0;
        __syncthreads();
        scn[t] += u;
        __syncthreads();
    }
    int ex = scn[t] - v;
    cur[t] = ex;
    int node = b * 512 + t;
    if (node < NN) rs[node] = gbase + ex;
    if (b == 0 && t == 0) rs[NN] = NE;
    __syncthreads();
    for (int i = t; i < cnt; i += 512) {
        int e = bs[i];
        int p = atomicAdd(&cur[e >> 17], 1);
        csrc[gbase + p] = e & 0x1FFFF;
    }
}

__global__ __launch_bounds__(256) void pos2_k(const float* __restrict__ pos,
                                              float2* __restrict__ pos2) {
    int n = blockIdx.x * 256 + threadIdx.x;
    if (n < NN) pos2[n] = make_float2(pos[n * 3], pos[n * 3 + 1]);
}

// ============================================================================
// One-shot weight packing (unchanged).
// ============================================================================
__global__ __launch_bounds__(256) void pack_all_k(
    const float* __restrict__ wl_stem, const float* __restrict__ wg_stem,
    const float* __restrict__ wl_c1, const float* __restrict__ bl_c1,
    const float* __restrict__ wl_c2, const float* __restrict__ bl_c2,
    const float* __restrict__ wg_c1, const float* __restrict__ wg_c2,
    const float* __restrict__ wl_reg, const float* __restrict__ wl_obj,
    const float* __restrict__ bl_reg, const float* __restrict__ bl_obj,
    const float* __restrict__ wl_cls, const float* __restrict__ wg_cls,
    float* __restrict__ wT_sp, float* __restrict__ wT_sg,
    float* __restrict__ wT_12, float* __restrict__ wT_g1,
    float* __restrict__ wT_g2, float* __restrict__ wT_ro,
    float* __restrict__ wT_cp, float* __restrict__ wT_cg,
    float* __restrict__ bAB, float* __restrict__ wro, float* __restrict__ bro) {
    int u = blockIdx.x * 256 + threadIdx.x;
    if (u < 4096) { int j = u >> 6, c = u & 63; wT_sp[u] = wl_stem[c * 66 + j]; return; }
    u -= 4096;
    if (u < 4096) { int j = u >> 6, c = u & 63; wT_sg[u] = wg_stem[c * 64 + j]; return; }
    u -= 4096;
    if (u < 8192) { int j = u >> 7, c = u & 127; int k = c >> 1;
        wT_12[u] = ((c & 1) ? wl_c2 : wl_c1)[k * 66 + j]; return; }
    u -= 8192;
    if (u < 4096) { int j = u >> 6, c = u & 63; wT_g1[u] = wg_c1[c * 64 + j]; return; }
    u -= 4096;
    if (u < 4096) { int j = u >> 6, c = u & 63; wT_g2[u] = wg_c2[c * 64 + j]; return; }
    u -= 4096;
    if (u < 1024) { int j = u >> 4, c = u & 15;
        wT_ro[u] = (c < 4) ? wl_reg[c * 66 + j] : ((c == 4) ? wl_obj[j] : 0.f); return; }
    u -= 1024;
    if (u < 7168) { int j = u / 112, c = u - j * 112;
        wT_cp[u] = (c < NCLS) ? wl_cls[c * 66 + j] : 0.f; return; }
    u -= 7168;
    if (u < 11312) { int j = u / 112, c = u - j * 112;
        wT_cg[u] = (c < NCLS) ? wg_cls[c * NCLS + j] : 0.f; return; }
    u -= 11312;
    if (u < 128) { bAB[u] = (u & 1) ? bl_c2[u >> 1] : bl_c1[u >> 1]; return; }
    u -= 128;
    if (u < 330) { int cc = u / 66, j = u - cc * 66;
        wro[u] = (cc < 4) ? wl_reg[u] : wl_obj[j]; return; }
    u -= 330;
    if (u < 5) bro[u] = (u < 4) ? bl_reg[u] : bl_obj[0];
}

// ============================================================================
// Node-side GEMM. BNF: fused BN+ReLU on input staging. STOUT: per-block
// sum/sumsq partials (no atomics). BOUT: bf16 output. XIN16: stage x-tile in
// bf16 (halves xs LDS -> keeps 2 blocks/CU at MT=128 with K=101).
// ============================================================================
template <int COUT, int CPW, int K, int IS, int OS, int MT, bool BNF, bool STOUT,
          bool BOUT, bool XIN16>
__global__ __launch_bounds__(256) void gemm_k(const float* __restrict__ in,
                                              const float* __restrict__ wT,
                                              const float* __restrict__ bias,
                                              const float* __restrict__ st,
                                              float* __restrict__ stpart,
                                              float* __restrict__ out) {
    constexpr int CP = 4 * CPW;
    constexpr int RM = MT / 64;
    constexpr int XR = MT + 1;
    __shared__ __align__(16) unsigned char xsraw[K * XR * (XIN16 ? 2 : 4)];
    __shared__ __align__(16) float wsh[K * CP];
    float* xs = (float*)xsraw;
    unsigned short* xs16 = (unsigned short*)xsraw;
    int base = blockIdx.x * MT;
    for (int p = threadIdx.x; p < K * CP / 4; p += 256)
        ((float4*)wsh)[p] = ((const float4*)wT)[p];
    for (int p = threadIdx.x; p < MT * K; p += 256) {
        int n = p / K, j = p - n * K;
        float v = (base + n < NN) ? in[(size_t)(base + n) * IS + j] : 0.f;
        if constexpr (BNF) v = fmaxf(fmaf(v, st[128 + j], st[192 + j]), 0.f);
        if constexpr (XIN16)
            xs16[j * XR + n] = __bfloat16_as_ushort(__float2bfloat16(v));
        else
            xs[j * XR + n] = v;
    }
    __syncthreads();
    int wid = __builtin_amdgcn_readfirstlane(threadIdx.x >> 6);
    int lane = threadIdx.x & 63;
    int c0 = wid * CPW;
    if (c0 >= COUT) return;     // after the only barrier -> safe
    float acc[RM][CPW];
#pragma unroll
    for (int k = 0; k < CPW; ++k) {
        float bv = (c0 + k < COUT) ? bias[c0 + k] : 0.f;
#pragma unroll
        for (int r = 0; r < RM; ++r) acc[r][k] = bv;
    }
    for (int j = 0; j < K; ++j) {
        float a[RM];
#pragma unroll
        for (int r = 0; r < RM; ++r) {
            if constexpr (XIN16)
                a[r] = b2f(xs16[j * XR + 64 * r + lane]);
            else
                a[r] = xs[j * XR + 64 * r + lane];
        }
#pragma unroll
        for (int q = 0; q < CPW / 4; ++q) {
            float4 wv = *(const float4*)&wsh[j * CP + c0 + 4 * q];
#pragma unroll
            for (int r = 0; r < RM; ++r) {
                acc[r][4 * q + 0] = fmaf(a[r], wv.x, acc[r][4 * q + 0]);
                acc[r][4 * q + 1] = fmaf(a[r], wv.y, acc[r][4 * q + 1]);
                acc[r][4 * q + 2] = fmaf(a[r], wv.z, acc[r][4 * q + 2]);
                acc[r][4 * q + 3] = fmaf(a[r], wv.w, acc[r][4 * q + 3]);
            }
        }
    }
#pragma unroll
    for (int r = 0; r < RM; ++r) {
        int node = base + 64 * r + lane;
        if (node < NN) {
#pragma unroll
            for (int k = 0; k < CPW; ++k) {
                if (c0 + k < COUT) {
                    if constexpr (BOUT) {
                        __hip_bfloat16* ob = (__hip_bfloat16*)out;
                        ob[(size_t)node * OS + c0 + k] = __float2bfloat16(acc[r][k]);
                    } else {
                        out[(size_t)node * OS + c0 + k] = acc[r][k];
                    }
                }
            }
        }
    }
    if constexpr (STOUT) {
        float* sp = stpart + (size_t)blockIdx.x * 128;
#pragma unroll
        for (int k = 0; k < CPW; ++k) {
            if (c0 + k < COUT) {
                float s = 0.f, q = 0.f;
#pragma unroll
                for (int r = 0; r < RM; ++r) {
                    float v = (base + 64 * r + lane < NN) ? acc[r][k] : 0.f;
                    s += v;
                    q = fmaf(v, v, q);
                }
#pragma unroll
                for (int off = 1; off < 64; off <<= 1) {
                    s += __shfl_xor(s, off, 64);
                    q += __shfl_xor(q, off, 64);
                }
                if (lane == 0) {
                    sp[c0 + k] = s;
                    sp[64 + c0 + k] = q;
                }
            }
        }
    }
}

// reduce per-block partials -> BN scale/shift. One block, 256 threads.
__global__ __launch_bounds__(256) void bnpar_k(const float* __restrict__ stpart,
                                               const float* __restrict__ g,
                                               const float* __restrict__ b,
                                               float* __restrict__ st, int nparts) {
    __shared__ float sS[4][64], sQ[4][64];
    int c = threadIdx.x & 63;
    int part = threadIdx.x >> 6;
    float s = 0.f, q = 0.f;
    for (int i = part; i < nparts; i += 4) {
        s += stpart[(size_t)i * 128 + c];
        q += stpart[(size_t)i * 128 + 64 + c];
    }
    sS[part][c] = s;
    sQ[part][c] = q;
    __syncthreads();
    if (part == 0) {
        s = sS[0][c] + sS[1][c] + sS[2][c] + sS[3][c];
        q = sQ[0][c] + sQ[1][c] + sQ[2][c] + sQ[3][c];
        float mu = s * (1.0f / NN);
        float var = q * (1.0f / NN) - mu * mu;
        float sc = g[c] * rsqrtf(var + EPS_BN);
        st[128 + c] = sc;
        st[192 + c] = b[c] - mu * sc;
    }
}

// ============================================================================
// Edge segment-max over CSR, bf16 payloads (R10, unchanged).
// ============================================================================
__global__ __launch_bounds__(256) void edge1_k(const unsigned short* __restrict__ y,  // bf16, stride 64
                                               const float2* __restrict__ pos2,
                                               const int* __restrict__ rs,
                                               const int* __restrict__ csrc,
                                               const float* __restrict__ wl,  // (64,66)
                                               float* __restrict__ agg) {
    int wid = __builtin_amdgcn_readfirstlane(threadIdx.x >> 6);
    int lane = threadIdx.x & 63;
    int node = blockIdx.x * 4 + wid;
    if (node >= NN) return;
    float wp0 = wl[lane * 66 + 64], wp1 = wl[lane * 66 + 65];
    float2 pd = pos2[node];
    int i0 = rs[node], i1 = rs[node + 1];
    float acc = NINF;
    for (int ib = i0; ib < i1; ib += 64) {
        int m = i1 - ib;
        if (m > 64) m = 64;
        int t = ib + lane;
        int idx = (t < i1) ? csrc[t] : 0;
        float2 pp = pos2[idx];
        float ppx = pp.x, ppy = pp.y;
        int j = 0;
        for (; j + 8 <= m; j += 8) {
            float v[8];
#pragma unroll
            for (int q = 0; q < 8; ++q)
                v[q] = b2f(y[(size_t)rl_i(idx, j + q) * 64 + lane]);
#pragma unroll
            for (int q = 0; q < 8; ++q) {
                float dx = rl_f(ppx, j + q) - pd.x, dy = rl_f(ppy, j + q) - pd.y;
                acc = fmaxf(acc, fmaf(dy, wp1, fmaf(dx, wp0, v[q])));
            }
        }
        for (; j < m; ++j) {
            float v = b2f(y[(size_t)rl_i(idx, j) * 64 + lane]);
            acc = fmaxf(acc, fmaf(rl_f(ppy, j) - pd.y, wp1,
                                  fmaf(rl_f(ppx, j) - pd.x, wp0, v)));
        }
    }
    agg[(size_t)node * 64 + lane] = fmaxf(acc, 0.0f);
}

// y12: bf16 [n][64]{c1,c2} pairs -> one uint per lane
__global__ __launch_bounds__(256) void edge2_k(const unsigned* __restrict__ y12,
                                               const float2* __restrict__ pos2,
                                               const int* __restrict__ rs,
                                               const int* __restrict__ csrc,
                                               const float* __restrict__ wlA,
                                               const float* __restrict__ wlB,
                                               float* __restrict__ a1,
                                               float* __restrict__ a2) {
    int wid = __builtin_amdgcn_readfirstlane(threadIdx.x >> 6);
    int lane = threadIdx.x & 63;
    int node = blockIdx.x * 4 + wid;
    if (node >= NN) return;
    float wa0 = wlA[lane * 66 + 64], wa1 = wlA[lane * 66 + 65];
    float wb0 = wlB[lane * 66 + 64], wb1 = wlB[lane * 66 + 65];
    float2 pd = pos2[node];
    int i0 = rs[node], i1 = rs[node + 1];
    float accA = NINF, accB = NINF;
    for (int ib = i0; ib < i1; ib += 64) {
        int m = i1 - ib;
        if (m > 64) m = 64;
        int t = ib + lane;
        int idx = (t < i1) ? csrc[t] : 0;
        float2 pp = pos2[idx];
        float ppx = pp.x, ppy = pp.y;
        int j = 0;
        for (; j + 8 <= m; j += 8) {
            unsigned w[8];
#pragma unroll
            for (int q = 0; q < 8; ++q)
                w[q] = y12[(size_t)rl_i(idx, j + q) * 64 + lane];
#pragma unroll
            for (int q = 0; q < 8; ++q) {
                float dx = rl_f(ppx, j + q) - pd.x, dy = rl_f(ppy, j + q) - pd.y;
                accA = fmaxf(accA, fmaf(dy, wa1, fmaf(dx, wa0,
                                        b2f((unsigned short)w[q]))));
                accB = fmaxf(accB, fmaf(dy, wb1, fmaf(dx, wb0,
                                        b2f((unsigned short)(w[q] >> 16)))));
            }
        }
        for (; j < m; ++j) {
            unsigned w = y12[(size_t)rl_i(idx, j) * 64 + lane];
            float dx = rl_f(ppx, j) - pd.x, dy = rl_f(ppy, j) - pd.y;
            accA = fmaxf(accA, fmaf(dy, wa1, fmaf(dx, wa0, b2f((unsigned short)w))));
            accB = fmaxf(accB, fmaf(dy, wb1, fmaf(dx, wb0,
                                    b2f((unsigned short)(w >> 16)))));
        }
    }
    a1[(size_t)node * 64 + lane] = fmaxf(accA, 0.0f);
    a2[(size_t)node * 64 + lane] = fmaxf(accB, 0.0f);
}

// cls: wave per node, lane covers channels {lane, lane+64 (clamped)}
__global__ __launch_bounds__(256) void edge_cls_k(const unsigned short* __restrict__ y,  // bf16, stride 104
                                                  const float2* __restrict__ pos2,
                                                  const int* __restrict__ rs,
                                                  const int* __restrict__ csrc,
                                                  const float* __restrict__ wl,  // (101,66)
                                                  float* __restrict__ agg) {     // fp32, stride 104
    int wid = __builtin_amdgcn_readfirstlane(threadIdx.x >> 6);
    int lane = threadIdx.x & 63;
    int node = blockIdx.x * 4 + wid;
    if (node >= NN) return;
    int chi = (lane + 64 < NCLS) ? (lane + 64) : (NCLS - 1);
    float wa0 = wl[lane * 66 + 64], wa1 = wl[lane * 66 + 65];
    float wb0 = wl[chi * 66 + 64], wb1 = wl[chi * 66 + 65];
    float2 pd = pos2[node];
    int i0 = rs[node], i1 = rs[node + 1];
    float accA = NINF, accB = NINF;
    for (int ib = i0; ib < i1; ib += 64) {
        int m = i1 - ib;
        if (m > 64) m = 64;
        int t = ib + lane;
        int idx = (t < i1) ? csrc[t] : 0;
        float2 pp = pos2[idx];
        float ppx = pp.x, ppy = pp.y;
        int j = 0;
        for (; j + 4 <= m; j += 4) {
            float va[4], vb[4];
#pragma unroll
            for (int q = 0; q < 4; ++q) {
                size_t row = (size_t)rl_i(idx, j + q) * 104;
                va[q] = b2f(y[row + lane]);
                vb[q] = b2f(y[row + chi]);
            }
#pragma unroll
            for (int q = 0; q < 4; ++q) {
                float dx = rl_f(ppx, j + q) - pd.x, dy = rl_f(ppy, j + q) - pd.y;
                accA = fmaxf(accA, fmaf(dy, wa1, fmaf(dx, wa0, va[q])));
                accB = fmaxf(accB, fmaf(dy, wb1, fmaf(dx, wb0, vb[q])));
            }
        }
        for (; j < m; ++j) {
            size_t row = (size_t)rl_i(idx, j) * 104;
            float va = b2f(y[row + lane]);
            float vb = b2f(y[row + chi]);
            float dx = rl_f(ppx, j) - pd.x, dy = rl_f(ppy, j) - pd.y;
            accA = fmaxf(accA, fmaf(dy, wa1, fmaf(dx, wa0, va)));
            accB = fmaxf(accB, fmaf(dy, wb1, fmaf(dx, wb0, vb)));
        }
    }
    agg[(size_t)node * 104 + lane] = fmaxf(accA, 0.0f);
    if (lane + 64 < NCLS) agg[(size_t)node * 104 + 64 + lane] = fmaxf(accB, 0.0f);
}

// reg+obj: 5 bf16 channels packed stride 8; wave = 8 edge-slots x 8 ch-slots
__global__ __launch_bounds__(256) void edge_ro_k(const unsigned short* __restrict__ y,  // bf16, stride 8
                                                 const float2* __restrict__ pos2,
                                                 const int* __restrict__ rs,
                                                 const int* __restrict__ csrc,
                                                 const float* __restrict__ wro,  // (5,66)
                                                 float* __restrict__ aggr,
                                                 float* __restrict__ aggo) {
    int wid = __builtin_amdgcn_readfirstlane(threadIdx.x >> 6);
    int lane = threadIdx.x & 63;
    int node = blockIdx.x * 4 + wid;
    if (node >= NN) return;
    int k = lane >> 3, c = lane & 7;
    int cc = (c < 5) ? c : 4;
    float wp0 = wro[cc * 66 + 64], wp1 = wro[cc * 66 + 65];
    float2 pd = pos2[node];
    int i0 = rs[node], i1 = rs[node + 1];
    float acc = NINF;
    for (int i = i0 + k; i < i1; i += 8) {
        int s = csrc[i];
        float2 p = pos2[s];
        float v = b2f(y[(size_t)s * 8 + cc]);
        acc = fmaxf(acc, fmaf(p.y - pd.y, wp1, fmaf(p.x - pd.x, wp0, v)));
    }
    acc = fmaxf(acc, __shfl_xor(acc, 8, 64));
    acc = fmaxf(acc, __shfl_xor(acc, 16, 64));
    acc = fmaxf(acc, __shfl_xor(acc, 32, 64));
    acc = fmaxf(acc, 0.0f);
    if (lane < 5) {
        if (lane < 4) aggr[(size_t)node * 4 + lane] = acc;
        else          aggo[node] = acc;
    }
}

__global__ __launch_bounds__(256) void final_ro_k(const float* __restrict__ aggr,
                                                  const float* __restrict__ aggo,
                                                  const float* __restrict__ wgr,
                                                  const float* __restrict__ bgr,
                                                  const float* __restrict__ wgo,
                                                  const float* __restrict__ bgo,
                                                  float* __restrict__ out) {
    int n = blockIdx.x * 256 + threadIdx.x;
    if (n >= NN) return;
    float a0 = aggr[(size_t)n * 4 + 0], a1 = aggr[(size_t)n * 4 + 1];
    float a2 = aggr[(size_t)n * 4 + 2], a3 = aggr[(size_t)n * 4 + 3];
    float* reg = out + (size_t)NN * NCLS;
    float* obj = reg + (size_t)NN * 4;
#pragma unroll
    for (int k = 0; k < 4; ++k) {
        float acc = bgr[k];
        acc = fmaf(a0, wgr[k * 4 + 0], acc);
        acc = fmaf(a1, wgr[k * 4 + 1], acc);
        acc = fmaf(a2, wgr[k * 4 + 2], acc);
        acc = fmaf(a3, wgr[k * 4 + 3], acc);
        reg[(size_t)n * 4 + k] = acc;
    }
    obj[n] = fmaf(aggo[n], wgo[0], bgo[0]);
}

// ============================================================================
extern "C" void kernel_launch(void* const* d_in, const int* in_sizes, int n_in,
                              void* d_out, int out_size, void* d_ws, size_t ws_size,
                              hipStream_t stream) {
    const float* x   = (const float*)d_in[0];
    const float* pos = (const float*)d_in[1];
    const int* ei    = (const int*)d_in[2];
    const int* src = ei;
    const int* dst = ei + NE;
    const float* wl_stem = (const float*)d_in[3];
    const float* bl_stem = (const float*)d_in[4];
    const float* wg_stem = (const float*)d_in[5];
    const float* bg_stem = (const float*)d_in[6];
    const float* g_stem  = (const float*)d_in[7];
    const float* b_stem  = (const float*)d_in[8];
    const float* wl_c1 = (const float*)d_in[9];
    const float* bl_c1 = (const float*)d_in[10];
    const float* wg_c1 = (const float*)d_in[11];
    const float* bg_c1 = (const float*)d_in[12];
    const float* g_c1  = (const float*)d_in[13];
    const float* b_c1  = (const float*)d_in[14];
    const float* wl_c2 = (const float*)d_in[15];
    const float* bl_c2 = (const float*)d_in[16];
    const float* wg_c2 = (const float*)d_in[17];
    const float* bg_c2 = (const float*)d_in[18];
    const float* g_c2  = (const float*)d_in[19];
    const float* b_c2  = (const float*)d_in[20];
    const float* wl_reg = (const float*)d_in[21];
    const float* bl_reg = (const float*)d_in[22];
    const float* wg_reg = (const float*)d_in[23];
    const float* bg_reg = (const float*)d_in[24];
    const float* wl_cls = (const float*)d_in[25];
    const float* bl_cls = (const float*)d_in[26];
    const float* wg_cls = (const float*)d_in[27];
    const float* bg_cls = (const float*)d_in[28];
    const float* wl_obj = (const float*)d_in[29];
    const float* bl_obj = (const float*)d_in[30];
    const float* wg_obj = (const float*)d_in[31];
    const float* bg_obj = (const float*)d_in[32];

    float* ws = (float*)d_ws;
    // Arena: S0[N*128] | S1[N*64] | S2[N*64] | S3[N*64] | ints/smalls
    float* S0 = ws;
    float* S1 = S0 + (size_t)NN * 128;
    float* S2 = S1 + (size_t)NN * 64;
    float* S3 = S2 + (size_t)NN * 64;
    float* y12   = S0;       // bf16 [n][128]
    float* y_cls = S0;       // bf16 [n][104]
    float* aggc  = S1;       // fp32 N*104 spans S1+S2 (both dead by then)
    int*   bstore = (int*)S0;                     // NBUCK*BCAP ints
    int*   rs   = (int*)(S3 + (size_t)NN * 64);   // NN+1 (padded to 100016)
    int*   csrc = rs + 100016;                    // NE
    float* pos2 = (float*)(csrc + NE);            // NN float2
    float* y_ro = pos2 + (size_t)NN * 2;          // bf16 [n][8] (slot sized for fp32)
    float* aggr = y_ro + (size_t)NN * 8;          // NN*4
    float* aggo = aggr + (size_t)NN * 4;          // NN
    float* st   = aggo + NN;                      // 3*256 (params at [128..255])
    float* st0 = st, *st1 = st + 256, *st2 = st + 512;
    float* wro = st + 768;                        // 336
    float* bro = wro + 336;                       // 8
    int*   bcnt16 = (int*)(bro + 8);              // NBUCK*16 (line-padded)
    int*   bbase  = bcnt16 + NBUCK * 16;          // 256
    float* wT_sp = (float*)(bbase + 256);         // [64][64]
    float* wT_sg = wT_sp + 4096;
    float* wT_12 = wT_sg + 4096;                  // [64][128]
    float* wT_g1 = wT_12 + 8192;
    float* wT_g2 = wT_g1 + 4096;
    float* wT_ro = wT_g2 + 4096;                  // [64][16]
    float* wT_cp = wT_ro + 1024;                  // [64][112]
    float* wT_cg = wT_cp + 7168;                  // [101][112]
    float* bAB   = wT_cg + 11312;                 // 128
    float* stpart = bAB + 128;                    // G128B*128 partials (400 KB)

    hipMemsetAsync(bcnt16, 0, NBUCK * 16 * sizeof(int), stream);

    const int NB = (NN + 255) / 256;      // 391
    const int N4 = (NN + 3) / 4;          // 25000
    const int CB = (NE + CHUNK - 1) / CHUNK;  // 782 binning blocks

    // ---- packing + CSR build + pos2 ----
    pack_all_k<<<175, 256, 0, stream>>>(wl_stem, wg_stem, wl_c1, bl_c1, wl_c2,
                                        bl_c2, wg_c1, wg_c2, wl_reg, wl_obj,
                                        bl_reg, bl_obj, wl_cls, wg_cls,
                                        wT_sp, wT_sg, wT_12, wT_g1, wT_g2,
                                        wT_ro, wT_cp, wT_cg, bAB, wro, bro);
    pos2_k<<<NB, 256, 0, stream>>>(pos, (float2*)pos2);
    bucket_k<<<CB, 256, 0, stream>>>(src, dst, bcnt16, bstore);
    bscan_k<<<1, 256, 0, stream>>>(bcnt16, bbase);
    b2csr_k<<<NBUCK, 512, 0, stream>>>(bcnt16, bbase, bstore, rs, csrc);

    // ---- stem ----
    gemm_k<64, 16, 64, 64, 64, 192, false, false, true, false><<<G192B, 256, 0, stream>>>(
        x, wT_sp, bl_stem, nullptr, nullptr, S1);          // y_stem bf16 in S1
    edge1_k<<<N4, 256, 0, stream>>>((const unsigned short*)S1, (float2*)pos2, rs,
                                    csrc, wl_stem, S2);
    gemm_k<64, 16, 64, 64, 64, 192, false, true, false, false><<<G192B, 256, 0, stream>>>(
        S2, wT_sg, bg_stem, nullptr, stpart, S2);
    bnpar_k<<<1, 256, 0, stream>>>(stpart, g_stem, b_stem, st0, G192B);

    // ---- c1 + c2 (BN fused into packed projection, shared edge pass) ----
    gemm_k<128, 32, 64, 64, 128, 128, true, false, true, false><<<G128B, 256, 0, stream>>>(
        S2, wT_12, bAB, st0, nullptr, y12);                // y12 bf16
    edge2_k<<<N4, 256, 0, stream>>>((const unsigned*)y12, (float2*)pos2, rs, csrc,
                                    wl_c1, wl_c2, S1, S3);
    gemm_k<64, 16, 64, 64, 64, 192, false, true, false, false><<<G192B, 256, 0, stream>>>(
        S1, wT_g1, bg_c1, nullptr, stpart, S1);
    bnpar_k<<<1, 256, 0, stream>>>(stpart, g_c1, b_c1, st1, G192B);
    gemm_k<64, 16, 64, 64, 64, 192, false, true, false, false><<<G192B, 256, 0, stream>>>(
        S3, wT_g2, bg_c2, nullptr, stpart, S3);
    bnpar_k<<<1, 256, 0, stream>>>(stpart, g_c2, b_c2, st2, G192B);

    // ---- reg + obj heads (input x1 = BN(S1), fused) ----
    gemm_k<5, 4, 64, 64, 8, 192, true, false, true, false><<<G192B, 256, 0, stream>>>(
        S1, wT_ro, bro, st1, nullptr, y_ro);               // y_ro bf16
    edge_ro_k<<<N4, 256, 0, stream>>>((const unsigned short*)y_ro, (float2*)pos2,
                                      rs, csrc, wro, aggr, aggo);

    // ---- cls head (input x2 = BN(S3), fused) ----
    gemm_k<101, 28, 64, 64, 104, 128, true, false, true, false><<<G128B, 256, 0, stream>>>(
        S3, wT_cp, bl_cls, st2, nullptr, y_cls);           // y_cls bf16
    edge_cls_k<<<N4, 256, 0, stream>>>((const unsigned short*)y_cls, (float2*)pos2,
                                       rs, csrc, wl_cls, aggc);
    gemm_k<101, 28, 101, 104, 101, 128, false, false, false, true><<<G128B, 256, 0, stream>>>(
        aggc, wT_cg, bg_cls, nullptr, nullptr, (float*)d_out);
    final_ro_k<<<NB, 256, 0, stream>>>(aggr, aggo, wg_reg, bg_reg, wg_obj, bg_obj,
                                       (float*)d_out);
}

// Round 13
// 905.962 us; speedup vs baseline: 1.1334x; 1.0841x over previous
//
#include <hip/hip_runtime.h>
#include <hip/hip_bf16.h>

#define NN 100000
#define NE 1600000
#define NCLS 101
#define EPS_BN 1e-5f
#define NINF (-__builtin_inff())
#define NBUCK 196      // ceil(NN/512)
#define BCAP 12288     // max edges/bucket (mean 8163, sd ~90)
#define G128B 782      // ceil(NN/128)
#define G192B 521      // ceil(NN/192)
#define CHUNK 2048     // edges per binning block

typedef __attribute__((ext_vector_type(8))) short bf16x8;
typedef __attribute__((ext_vector_type(4))) float f32x4;

__device__ __forceinline__ int rl_i(int v, int j) {
    return __builtin_amdgcn_readlane(v, j);
}
__device__ __forceinline__ float rl_f(float v, int j) {
    return __int_as_float(__builtin_amdgcn_readlane(__float_as_int(v), j));
}
__device__ __forceinline__ float b2f(unsigned short u) {
    return __uint_as_float(((unsigned)u) << 16);
}
__device__ __forceinline__ unsigned short f2b(float v) {
    return __bfloat16_as_ushort(__float2bfloat16(v));
}

// ============================================================================
// CSR build, bucketed with block-level binning (R9, unchanged).
// ============================================================================
__global__ __launch_bounds__(256) void bucket_k(const int* __restrict__ src,
                                                const int* __restrict__ dst,
                                                int* __restrict__ bcnt16,
                                                int* __restrict__ bstore) {
    __shared__ int vals[CHUNK];
    __shared__ int sval[CHUNK];
    __shared__ unsigned char bks[CHUNK];
    __shared__ unsigned char sbk[CHUNK];
    __shared__ int hist[256];
    __shared__ int scn[256];
    __shared__ int loff[256];
    __shared__ int cur[256];
    __shared__ int gshift[256];
    int e0 = blockIdx.x * CHUNK;
    int cnt = NE - e0;
    if (cnt > CHUNK) cnt = CHUNK;
    int t = threadIdx.x;
    hist[t] = 0;
    __syncthreads();
    for (int i = t; i < cnt; i += 256) {
        int d = dst[e0 + i], s = src[e0 + i];
        int b = d >> 9;
        vals[i] = ((d & 511) << 17) | s;
        bks[i] = (unsigned char)b;
        atomicAdd(&hist[b], 1);
    }
    __syncthreads();
    int v = hist[t];
    scn[t] = v;
    __syncthreads();
    for (int off = 1; off < 256; off <<= 1) {
        int u = (t >= off) ? scn[t - off] : 0;
        __syncthreads();
        scn[t] += u;
        __syncthreads();
    }
    loff[t] = scn[t] - v;
    cur[t] = scn[t] - v;
    if (t < NBUCK) {
        int base = (v > 0) ? atomicAdd(&bcnt16[t * 16], v) : 0;
        gshift[t] = base - loff[t];
    }
    __syncthreads();
    for (int i = t; i < cnt; i += 256) {
        int b = bks[i];
        int p = atomicAdd(&cur[b], 1);
        sval[p] = vals[i];
        sbk[p] = (unsigned char)b;
    }
    __syncthreads();
    for (int i = t; i < cnt; i += 256) {
        int b = sbk[i];
        int q = gshift[b] + i;
        if (q < BCAP) bstore[(size_t)b * BCAP + q] = sval[i];
    }
}

__global__ __launch_bounds__(256) void bscan_k(const int* __restrict__ bcnt16,
                                               int* __restrict__ bbase) {
    __shared__ int sh[256];
    int t = threadIdx.x;
    int v = (t < NBUCK) ? bcnt16[t * 16] : 0;
    sh[t] = v;
    __syncthreads();
    for (int off = 1; off < 256; off <<= 1) {
        int u = (t >= off) ? sh[t - off] : 0;
        __syncthreads();
        sh[t] += u;
        __syncthreads();
    }
    if (t < NBUCK) bbase[t] = sh[t] - v;
}

__global__ __launch_bounds__(512) void b2csr_k(const int* __restrict__ bcnt16,
                                               const int* __restrict__ bbase,
                                               const int* __restrict__ bstore,
                                               int* __restrict__ rs,
                                               int* __restrict__ csrc) {
    __shared__ int hist[512];
    __shared__ int scn[512];
    __shared__ int cur[512];
    int b = blockIdx.x;
    int t = threadIdx.x;
    int cnt = bcnt16[b * 16];
    if (cnt > BCAP) cnt = BCAP;
    int gbase = bbase[b];
    const int* bs = bstore + (size_t)b * BCAP;
    hist[t] = 0;
    __syncthreads();
    for (int i = t; i < cnt; i += 512) atomicAdd(&hist[bs[i] >> 17], 1);
    __syncthreads();
    int v = hist[t];
    scn[t] = v;
    __syncthreads();
    for (int off = 1; off < 512; off <<= 1) {
        int u = (t >= off) ? scn[t - off] : 0;
        __syncthreads();
        scn[t] += u;
        __syncthreads();
    }
    int ex = scn[t] - v;
    cur[t] = ex;
    int node = b * 512 + t;
    if (node < NN) rs[node] = gbase + ex;
    if (b == 0 && t == 0) rs[NN] = NE;
    __syncthreads();
    for (int i = t; i < cnt; i += 512) {
        int e = bs[i];
        int p = atomicAdd(&cur[e >> 17], 1);
        csrc[gbase + p] = e & 0x1FFFF;
    }
}

__global__ __launch_bounds__(256) void pos2_k(const float* __restrict__ pos,
                                              float2* __restrict__ pos2) {
    int n = blockIdx.x * 256 + threadIdx.x;
    if (n < NN) pos2[n] = make_float2(pos[n * 3], pos[n * 3 + 1]);
}

// ============================================================================
// One-shot weight packing. wg_cls packed bf16 [7][16 n][128 k] for MFMA B.
// ============================================================================
__global__ __launch_bounds__(256) void pack_all_k(
    const float* __restrict__ wl_stem, const float* __restrict__ wg_stem,
    const float* __restrict__ wl_c1, const float* __restrict__ bl_c1,
    const float* __restrict__ wl_c2, const float* __restrict__ bl_c2,
    const float* __restrict__ wg_c1, const float* __restrict__ wg_c2,
    const float* __restrict__ wl_reg, const float* __restrict__ wl_obj,
    const float* __restrict__ bl_reg, const float* __restrict__ bl_obj,
    const float* __restrict__ wl_cls, const float* __restrict__ wg_cls,
    float* __restrict__ wT_sp, float* __restrict__ wT_sg,
    float* __restrict__ wT_12, float* __restrict__ wT_g1,
    float* __restrict__ wT_g2, float* __restrict__ wT_ro,
    float* __restrict__ wT_cp, unsigned short* __restrict__ wcg16,
    float* __restrict__ bAB, float* __restrict__ wro, float* __restrict__ bro) {
    int u = blockIdx.x * 256 + threadIdx.x;
    if (u < 4096) { int j = u >> 6, c = u & 63; wT_sp[u] = wl_stem[c * 66 + j]; return; }
    u -= 4096;
    if (u < 4096) { int j = u >> 6, c = u & 63; wT_sg[u] = wg_stem[c * 64 + j]; return; }
    u -= 4096;
    if (u < 8192) { int j = u >> 7, c = u & 127; int k = c >> 1;
        wT_12[u] = ((c & 1) ? wl_c2 : wl_c1)[k * 66 + j]; return; }
    u -= 8192;
    if (u < 4096) { int j = u >> 6, c = u & 63; wT_g1[u] = wg_c1[c * 64 + j]; return; }
    u -= 4096;
    if (u < 4096) { int j = u >> 6, c = u & 63; wT_g2[u] = wg_c2[c * 64 + j]; return; }
    u -= 4096;
    if (u < 1024) { int j = u >> 4, c = u & 15;
        wT_ro[u] = (c < 4) ? wl_reg[c * 66 + j] : ((c == 4) ? wl_obj[j] : 0.f); return; }
    u -= 1024;
    if (u < 7168) { int j = u / 112, c = u - j * 112;
        wT_cp[u] = (c < NCLS) ? wl_cls[c * 66 + j] : 0.f; return; }
    u -= 7168;
    if (u < 14336) {   // wcg16[t][n][k]: B[k][n_global] = wg_cls[n_global][k]
        int k = u & 127;
        int n = (u >> 7) & 15;
        int t2 = u >> 11;
        int ng = t2 * 16 + n;
        float v = (ng < NCLS && k < NCLS) ? wg_cls[ng * NCLS + k] : 0.f;
        wcg16[u] = f2b(v);
        return;
    }
    u -= 14336;
    if (u < 128) { bAB[u] = (u & 1) ? bl_c2[u >> 1] : bl_c1[u >> 1]; return; }
    u -= 128;
    if (u < 330) { int cc = u / 66, j = u - cc * 66;
        wro[u] = (cc < 4) ? wl_reg[u] : wl_obj[j]; return; }
    u -= 330;
    if (u < 5) bro[u] = (u < 4) ? bl_reg[u] : bl_obj[0];
}

// ============================================================================
// Node-side GEMM (vector-ALU path; unchanged from R12 minus XIN16 use).
// ============================================================================
template <int COUT, int CPW, int K, int IS, int OS, int MT, bool BNF, bool STOUT,
          bool BOUT>
__global__ __launch_bounds__(256) void gemm_k(const float* __restrict__ in,
                                              const float* __restrict__ wT,
                                              const float* __restrict__ bias,
                                              const float* __restrict__ st,
                                              float* __restrict__ stpart,
                                              float* __restrict__ out) {
    constexpr int CP = 4 * CPW;
    constexpr int RM = MT / 64;
    constexpr int XR = MT + 1;
    __shared__ __align__(16) float xs[K * XR];
    __shared__ __align__(16) float wsh[K * CP];
    int base = blockIdx.x * MT;
    for (int p = threadIdx.x; p < K * CP / 4; p += 256)
        ((float4*)wsh)[p] = ((const float4*)wT)[p];
    for (int p = threadIdx.x; p < MT * K; p += 256) {
        int n = p / K, j = p - n * K;
        float v = (base + n < NN) ? in[(size_t)(base + n) * IS + j] : 0.f;
        if constexpr (BNF) v = fmaxf(fmaf(v, st[128 + j], st[192 + j]), 0.f);
        xs[j * XR + n] = v;
    }
    __syncthreads();
    int wid = __builtin_amdgcn_readfirstlane(threadIdx.x >> 6);
    int lane = threadIdx.x & 63;
    int c0 = wid * CPW;
    if (c0 >= COUT) return;
    float acc[RM][CPW];
#pragma unroll
    for (int k = 0; k < CPW; ++k) {
        float bv = (c0 + k < COUT) ? bias[c0 + k] : 0.f;
#pragma unroll
        for (int r = 0; r < RM; ++r) acc[r][k] = bv;
    }
    for (int j = 0; j < K; ++j) {
        float a[RM];
#pragma unroll
        for (int r = 0; r < RM; ++r) a[r] = xs[j * XR + 64 * r + lane];
#pragma unroll
        for (int q = 0; q < CPW / 4; ++q) {
            float4 wv = *(const float4*)&wsh[j * CP + c0 + 4 * q];
#pragma unroll
            for (int r = 0; r < RM; ++r) {
                acc[r][4 * q + 0] = fmaf(a[r], wv.x, acc[r][4 * q + 0]);
                acc[r][4 * q + 1] = fmaf(a[r], wv.y, acc[r][4 * q + 1]);
                acc[r][4 * q + 2] = fmaf(a[r], wv.z, acc[r][4 * q + 2]);
                acc[r][4 * q + 3] = fmaf(a[r], wv.w, acc[r][4 * q + 3]);
            }
        }
    }
#pragma unroll
    for (int r = 0; r < RM; ++r) {
        int node = base + 64 * r + lane;
        if (node < NN) {
#pragma unroll
            for (int k = 0; k < CPW; ++k) {
                if (c0 + k < COUT) {
                    if constexpr (BOUT) {
                        __hip_bfloat16* ob = (__hip_bfloat16*)out;
                        ob[(size_t)node * OS + c0 + k] = __float2bfloat16(acc[r][k]);
                    } else {
                        out[(size_t)node * OS + c0 + k] = acc[r][k];
                    }
                }
            }
        }
    }
    if constexpr (STOUT) {
        float* sp = stpart + (size_t)blockIdx.x * 128;
#pragma unroll
        for (int k = 0; k < CPW; ++k) {
            if (c0 + k < COUT) {
                float s = 0.f, q = 0.f;
#pragma unroll
                for (int r = 0; r < RM; ++r) {
                    float v = (base + 64 * r + lane < NN) ? acc[r][k] : 0.f;
                    s += v;
                    q = fmaf(v, v, q);
                }
#pragma unroll
                for (int off = 1; off < 64; off <<= 1) {
                    s += __shfl_xor(s, off, 64);
                    q += __shfl_xor(q, off, 64);
                }
                if (lane == 0) {
                    sp[c0 + k] = s;
                    sp[64 + c0 + k] = q;
                }
            }
        }
    }
}

// ============================================================================
// MFMA final cls GEMM: out[m][n] = sum_k aggc16[m][k]*wg_cls[n][k] + bg[n].
// aggc16 bf16 [rows][128] (cols 101.. zero); wcg16 bf16 [7][16 n][128 k].
// Wave per 16-row M-tile; A frag m=lane&15,k=quad*8+j; C/D col=lane&15,
// row=quad*4+reg (verified layouts). No LDS, no barrier.
// ============================================================================
__global__ __launch_bounds__(256) void mfma_cls_k(
    const unsigned short* __restrict__ aggc16,
    const unsigned short* __restrict__ wcg16,
    const float* __restrict__ bgc,
    float* __restrict__ out) {
    int wid = __builtin_amdgcn_readfirstlane(threadIdx.x >> 6);
    int lane = threadIdx.x & 63;
    int quad = lane >> 4;
    int l16 = lane & 15;
    int mbase = blockIdx.x * 64 + wid * 16;
    bf16x8 a[4];
    const unsigned short* arow = aggc16 + (size_t)(mbase + l16) * 128 + quad * 8;
#pragma unroll
    for (int kc = 0; kc < 4; ++kc)
        a[kc] = *(const bf16x8*)(arow + kc * 32);
    for (int t = 0; t < 7; ++t) {
        const unsigned short* brow = wcg16 + t * 2048 + l16 * 128 + quad * 8;
        f32x4 acc = {0.f, 0.f, 0.f, 0.f};
#pragma unroll
        for (int kc = 0; kc < 4; ++kc) {
            bf16x8 b = *(const bf16x8*)(brow + kc * 32);
            acc = __builtin_amdgcn_mfma_f32_16x16x32_bf16(a[kc], b, acc, 0, 0, 0);
        }
        int cg = t * 16 + l16;
        if (cg < NCLS) {
            float bv = bgc[cg];
#pragma unroll
            for (int r = 0; r < 4; ++r) {
                int rg = mbase + quad * 4 + r;
                if (rg < NN) out[(size_t)rg * NCLS + cg] = acc[r] + bv;
            }
        }
    }
}

// reduce per-block partials -> BN scale/shift. One block, 256 threads.
__global__ __launch_bounds__(256) void bnpar_k(const float* __restrict__ stpart,
                                               const float* __restrict__ g,
                                               const float* __restrict__ b,
                                               float* __restrict__ st, int nparts) {
    __shared__ float sS[4][64], sQ[4][64];
    int c = threadIdx.x & 63;
    int part = threadIdx.x >> 6;
    float s = 0.f, q = 0.f;
    for (int i = part; i < nparts; i += 4) {
        s += stpart[(size_t)i * 128 + c];
        q += stpart[(size_t)i * 128 + 64 + c];
    }
    sS[part][c] = s;
    sQ[part][c] = q;
    __syncthreads();
    if (part == 0) {
        s = sS[0][c] + sS[1][c] + sS[2][c] + sS[3][c];
        q = sQ[0][c] + sQ[1][c] + sQ[2][c] + sQ[3][c];
        float mu = s * (1.0f / NN);
        float var = q * (1.0f / NN) - mu * mu;
        float sc = g[c] * rsqrtf(var + EPS_BN);
        st[128 + c] = sc;
        st[192 + c] = b[c] - mu * sc;
    }
}

// ============================================================================
// Edge segment-max over CSR, bf16 payloads.
// ============================================================================
__global__ __launch_bounds__(256) void edge1_k(const unsigned short* __restrict__ y,  // bf16, stride 64
                                               const float2* __restrict__ pos2,
                                               const int* __restrict__ rs,
                                               const int* __restrict__ csrc,
                                               const float* __restrict__ wl,  // (64,66)
                                               float* __restrict__ agg) {
    int wid = __builtin_amdgcn_readfirstlane(threadIdx.x >> 6);
    int lane = threadIdx.x & 63;
    int node = blockIdx.x * 4 + wid;
    if (node >= NN) return;
    float wp0 = wl[lane * 66 + 64], wp1 = wl[lane * 66 + 65];
    float2 pd = pos2[node];
    int i0 = rs[node], i1 = rs[node + 1];
    float acc = NINF;
    for (int ib = i0; ib < i1; ib += 64) {
        int m = i1 - ib;
        if (m > 64) m = 64;
        int t = ib + lane;
        int idx = (t < i1) ? csrc[t] : 0;
        float2 pp = pos2[idx];
        float ppx = pp.x, ppy = pp.y;
        int j = 0;
        for (; j + 8 <= m; j += 8) {
            float v[8];
#pragma unroll
            for (int q = 0; q < 8; ++q)
                v[q] = b2f(y[(size_t)rl_i(idx, j + q) * 64 + lane]);
#pragma unroll
            for (int q = 0; q < 8; ++q) {
                float dx = rl_f(ppx, j + q) - pd.x, dy = rl_f(ppy, j + q) - pd.y;
                acc = fmaxf(acc, fmaf(dy, wp1, fmaf(dx, wp0, v[q])));
            }
        }
        for (; j < m; ++j) {
            float v = b2f(y[(size_t)rl_i(idx, j) * 64 + lane]);
            acc = fmaxf(acc, fmaf(rl_f(ppy, j) - pd.y, wp1,
                                  fmaf(rl_f(ppx, j) - pd.x, wp0, v)));
        }
    }
    agg[(size_t)node * 64 + lane] = fmaxf(acc, 0.0f);
}

// y12: bf16 [n][64]{c1,c2} pairs -> one uint per lane
__global__ __launch_bounds__(256) void edge2_k(const unsigned* __restrict__ y12,
                                               const float2* __restrict__ pos2,
                                               const int* __restrict__ rs,
                                               const int* __restrict__ csrc,
                                               const float* __restrict__ wlA,
                                               const float* __restrict__ wlB,
                                               float* __restrict__ a1,
                                               float* __restrict__ a2) {
    int wid = __builtin_amdgcn_readfirstlane(threadIdx.x >> 6);
    int lane = threadIdx.x & 63;
    int node = blockIdx.x * 4 + wid;
    if (node >= NN) return;
    float wa0 = wlA[lane * 66 + 64], wa1 = wlA[lane * 66 + 65];
    float wb0 = wlB[lane * 66 + 64], wb1 = wlB[lane * 66 + 65];
    float2 pd = pos2[node];
    int i0 = rs[node], i1 = rs[node + 1];
    float accA = NINF, accB = NINF;
    for (int ib = i0; ib < i1; ib += 64) {
        int m = i1 - ib;
        if (m > 64) m = 64;
        int t = ib + lane;
        int idx = (t < i1) ? csrc[t] : 0;
        float2 pp = pos2[idx];
        float ppx = pp.x, ppy = pp.y;
        int j = 0;
        for (; j + 8 <= m; j += 8) {
            unsigned w[8];
#pragma unroll
            for (int q = 0; q < 8; ++q)
                w[q] = y12[(size_t)rl_i(idx, j + q) * 64 + lane];
#pragma unroll
            for (int q = 0; q < 8; ++q) {
                float dx = rl_f(ppx, j + q) - pd.x, dy = rl_f(ppy, j + q) - pd.y;
                accA = fmaxf(accA, fmaf(dy, wa1, fmaf(dx, wa0,
                                        b2f((unsigned short)w[q]))));
                accB = fmaxf(accB, fmaf(dy, wb1, fmaf(dx, wb0,
                                        b2f((unsigned short)(w[q] >> 16)))));
            }
        }
        for (; j < m; ++j) {
            unsigned w = y12[(size_t)rl_i(idx, j) * 64 + lane];
            float dx = rl_f(ppx, j) - pd.x, dy = rl_f(ppy, j) - pd.y;
            accA = fmaxf(accA, fmaf(dy, wa1, fmaf(dx, wa0, b2f((unsigned short)w))));
            accB = fmaxf(accB, fmaf(dy, wb1, fmaf(dx, wb0,
                                    b2f((unsigned short)(w >> 16)))));
        }
    }
    a1[(size_t)node * 64 + lane] = fmaxf(accA, 0.0f);
    a2[(size_t)node * 64 + lane] = fmaxf(accB, 0.0f);
}

// cls: wave per node, lanes cover channels {lane, lane+64}; writes bf16
// aggc16 [node][128] with cols 101..127 zeroed (MFMA K padding).
__global__ __launch_bounds__(256) void edge_cls_k(const unsigned short* __restrict__ y,  // bf16, stride 104
                                                  const float2* __restrict__ pos2,
                                                  const int* __restrict__ rs,
                                                  const int* __restrict__ csrc,
                                                  const float* __restrict__ wl,  // (101,66)
                                                  unsigned short* __restrict__ aggb) {  // bf16, stride 128
    int wid = __builtin_amdgcn_readfirstlane(threadIdx.x >> 6);
    int lane = threadIdx.x & 63;
    int node = blockIdx.x * 4 + wid;
    if (node >= NN) return;
    int chi = (lane + 64 < NCLS) ? (lane + 64) : (NCLS - 1);
    float wa0 = wl[lane * 66 + 64], wa1 = wl[lane * 66 + 65];
    float wb0 = wl[chi * 66 + 64], wb1 = wl[chi * 66 + 65];
    float2 pd = pos2[node];
    int i0 = rs[node], i1 = rs[node + 1];
    float accA = NINF, accB = NINF;
    for (int ib = i0; ib < i1; ib += 64) {
        int m = i1 - ib;
        if (m > 64) m = 64;
        int t = ib + lane;
        int idx = (t < i1) ? csrc[t] : 0;
        float2 pp = pos2[idx];
        float ppx = pp.x, ppy = pp.y;
        int j = 0;
        for (; j + 4 <= m; j += 4) {
            float va[4], vb[4];
#pragma unroll
            for (int q = 0; q < 4; ++q) {
                size_t row = (size_t)rl_i(idx, j + q) * 104;
                va[q] = b2f(y[row + lane]);
                vb[q] = b2f(y[row + chi]);
            }
#pragma unroll
            for (int q = 0; q < 4; ++q) {
                float dx = rl_f(ppx, j + q) - pd.x, dy = rl_f(ppy, j + q) - pd.y;
                accA = fmaxf(accA, fmaf(dy, wa1, fmaf(dx, wa0, va[q])));
                accB = fmaxf(accB, fmaf(dy, wb1, fmaf(dx, wb0, vb[q])));
            }
        }
        for (; j < m; ++j) {
            size_t row = (size_t)rl_i(idx, j) * 104;
            float va = b2f(y[row + lane]);
            float vb = b2f(y[row + chi]);
            float dx = rl_f(ppx, j) - pd.x, dy = rl_f(ppy, j) - pd.y;
            accA = fmaxf(accA, fmaf(dy, wa1, fmaf(dx, wa0, va)));
            accB = fmaxf(accB, fmaf(dy, wb1, fmaf(dx, wb0, vb)));
        }
    }
    aggb[(size_t)node * 128 + lane] = f2b(fmaxf(accA, 0.0f));
    unsigned short hb = (lane + 64 < NCLS) ? f2b(fmaxf(accB, 0.0f)) : (unsigned short)0;
    aggb[(size_t)node * 128 + 64 + lane] = hb;
}

// reg+obj: 5 bf16 channels packed stride 8; wave = 8 edge-slots x 8 ch-slots
__global__ __launch_bounds__(256) void edge_ro_k(const unsigned short* __restrict__ y,  // bf16, stride 8
                                                 const float2* __restrict__ pos2,
                                                 const int* __restrict__ rs,
                                                 const int* __restrict__ csrc,
                                                 const float* __restrict__ wro,  // (5,66)
                                                 float* __restrict__ aggr,
                                                 float* __restrict__ aggo) {
    int wid = __builtin_amdgcn_readfirstlane(threadIdx.x >> 6);
    int lane = threadIdx.x & 63;
    int node = blockIdx.x * 4 + wid;
    if (node >= NN) return;
    int k = lane >> 3, c = lane & 7;
    int cc = (c < 5) ? c : 4;
    float wp0 = wro[cc * 66 + 64], wp1 = wro[cc * 66 + 65];
    float2 pd = pos2[node];
    int i0 = rs[node], i1 = rs[node + 1];
    float acc = NINF;
    for (int i = i0 + k; i < i1; i += 8) {
        int s = csrc[i];
        float2 p = pos2[s];
        float v = b2f(y[(size_t)s * 8 + cc]);
        acc = fmaxf(acc, fmaf(p.y - pd.y, wp1, fmaf(p.x - pd.x, wp0, v)));
    }
    acc = fmaxf(acc, __shfl_xor(acc, 8, 64));
    acc = fmaxf(acc, __shfl_xor(acc, 16, 64));
    acc = fmaxf(acc, __shfl_xor(acc, 32, 64));
    acc = fmaxf(acc, 0.0f);
    if (lane < 5) {
        if (lane < 4) aggr[(size_t)node * 4 + lane] = acc;
        else          aggo[node] = acc;
    }
}

__global__ __launch_bounds__(256) void final_ro_k(const float* __restrict__ aggr,
                                                  const float* __restrict__ aggo,
                                                  const float* __restrict__ wgr,
                                                  const float* __restrict__ bgr,
                                                  const float* __restrict__ wgo,
                                                  const float* __restrict__ bgo,
                                                  float* __restrict__ out) {
    int n = blockIdx.x * 256 + threadIdx.x;
    if (n >= NN) return;
    float a0 = aggr[(size_t)n * 4 + 0], a1 = aggr[(size_t)n * 4 + 1];
    float a2 = aggr[(size_t)n * 4 + 2], a3 = aggr[(size_t)n * 4 + 3];
    float* reg = out + (size_t)NN * NCLS;
    float* obj = reg + (size_t)NN * 4;
#pragma unroll
    for (int k = 0; k < 4; ++k) {
        float acc = bgr[k];
        acc = fmaf(a0, wgr[k * 4 + 0], acc);
        acc = fmaf(a1, wgr[k * 4 + 1], acc);
        acc = fmaf(a2, wgr[k * 4 + 2], acc);
        acc = fmaf(a3, wgr[k * 4 + 3], acc);
        reg[(size_t)n * 4 + k] = acc;
    }
    obj[n] = fmaf(aggo[n], wgo[0], bgo[0]);
}

// ============================================================================
extern "C" void kernel_launch(void* const* d_in, const int* in_sizes, int n_in,
                              void* d_out, int out_size, void* d_ws, size_t ws_size,
                              hipStream_t stream) {
    const float* x   = (const float*)d_in[0];
    const float* pos = (const float*)d_in[1];
    const int* ei    = (const int*)d_in[2];
    const int* src = ei;
    const int* dst = ei + NE;
    const float* wl_stem = (const float*)d_in[3];
    const float* bl_stem = (const float*)d_in[4];
    const float* wg_stem = (const float*)d_in[5];
    const float* bg_stem = (const float*)d_in[6];
    const float* g_stem  = (const float*)d_in[7];
    const float* b_stem  = (const float*)d_in[8];
    const float* wl_c1 = (const float*)d_in[9];
    const float* bl_c1 = (const float*)d_in[10];
    const float* wg_c1 = (const float*)d_in[11];
    const float* bg_c1 = (const float*)d_in[12];
    const float* g_c1  = (const float*)d_in[13];
    const float* b_c1  = (const float*)d_in[14];
    const float* wl_c2 = (const float*)d_in[15];
    const float* bl_c2 = (const float*)d_in[16];
    const float* wg_c2 = (const float*)d_in[17];
    const float* bg_c2 = (const float*)d_in[18];
    const float* g_c2  = (const float*)d_in[19];
    const float* b_c2  = (const float*)d_in[20];
    const float* wl_reg = (const float*)d_in[21];
    const float* bl_reg = (const float*)d_in[22];
    const float* wg_reg = (const float*)d_in[23];
    const float* bg_reg = (const float*)d_in[24];
    const float* wl_cls = (const float*)d_in[25];
    const float* bl_cls = (const float*)d_in[26];
    const float* wg_cls = (const float*)d_in[27];
    const float* bg_cls = (const float*)d_in[28];
    const float* wl_obj = (const float*)d_in[29];
    const float* bl_obj = (const float*)d_in[30];
    const float* wg_obj = (const float*)d_in[31];
    const float* bg_obj = (const float*)d_in[32];

    float* ws = (float*)d_ws;
    // Arena: S0[N*128] | S1[N*64] | S2[N*64] | S3[N*64] | ints/smalls
    float* S0 = ws;
    float* S1 = S0 + (size_t)NN * 128;
    float* S2 = S1 + (size_t)NN * 64;
    float* S3 = S2 + (size_t)NN * 64;
    float* y12   = S0;       // bf16 [n][128]
    float* y_cls = S0;       // bf16 [n][104]
    // aggc16: bf16 [n][128] in S1 (rows beyond NN spill into dead S2 space)
    unsigned short* aggc16 = (unsigned short*)S1;
    int*   bstore = (int*)S0;                     // NBUCK*BCAP ints
    int*   rs   = (int*)(S3 + (size_t)NN * 64);   // NN+1 (padded to 100016)
    int*   csrc = rs + 100016;                    // NE
    float* pos2 = (float*)(csrc + NE);            // NN float2
    float* y_ro = pos2 + (size_t)NN * 2;          // bf16 [n][8] (slot sized for fp32)
    float* aggr = y_ro + (size_t)NN * 8;          // NN*4
    float* aggo = aggr + (size_t)NN * 4;          // NN
    float* st   = aggo + NN;                      // 3*256 (params at [128..255])
    float* st0 = st, *st1 = st + 256, *st2 = st + 512;
    float* wro = st + 768;                        // 336
    float* bro = wro + 336;                       // 8
    int*   bcnt16 = (int*)(bro + 8);              // NBUCK*16 (line-padded)
    int*   bbase  = bcnt16 + NBUCK * 16;          // 256
    float* wT_sp = (float*)(bbase + 256);         // [64][64]
    float* wT_sg = wT_sp + 4096;
    float* wT_12 = wT_sg + 4096;                  // [64][128]
    float* wT_g1 = wT_12 + 8192;
    float* wT_g2 = wT_g1 + 4096;
    float* wT_ro = wT_g2 + 4096;                  // [64][16]
    float* wT_cp = wT_ro + 1024;                  // [64][112]
    unsigned short* wcg16 = (unsigned short*)(wT_cp + 7168);  // [7][16][128] bf16
    float* bAB   = wT_cp + 7168 + 7168;           // 128 (wcg16 = 14336 ushort = 7168 f)
    float* stpart = bAB + 128;                    // G128B*128 partials (400 KB)

    hipMemsetAsync(bcnt16, 0, NBUCK * 16 * sizeof(int), stream);

    const int NB = (NN + 255) / 256;      // 391
    const int N4 = (NN + 3) / 4;          // 25000
    const int CB = (NE + CHUNK - 1) / CHUNK;  // 782 binning blocks
    const int MB = (NN + 63) / 64;        // 1563 mfma cls blocks

    // ---- packing + CSR build + pos2 ----
    pack_all_k<<<186, 256, 0, stream>>>(wl_stem, wg_stem, wl_c1, bl_c1, wl_c2,
                                        bl_c2, wg_c1, wg_c2, wl_reg, wl_obj,
                                        bl_reg, bl_obj, wl_cls, wg_cls,
                                        wT_sp, wT_sg, wT_12, wT_g1, wT_g2,
                                        wT_ro, wT_cp, wcg16, bAB, wro, bro);
    pos2_k<<<NB, 256, 0, stream>>>(pos, (float2*)pos2);
    bucket_k<<<CB, 256, 0, stream>>>(src, dst, bcnt16, bstore);
    bscan_k<<<1, 256, 0, stream>>>(bcnt16, bbase);
    b2csr_k<<<NBUCK, 512, 0, stream>>>(bcnt16, bbase, bstore, rs, csrc);

    // ---- stem ----
    gemm_k<64, 16, 64, 64, 64, 192, false, false, true><<<G192B, 256, 0, stream>>>(
        x, wT_sp, bl_stem, nullptr, nullptr, S1);          // y_stem bf16 in S1
    edge1_k<<<N4, 256, 0, stream>>>((const unsigned short*)S1, (float2*)pos2, rs,
                                    csrc, wl_stem, S2);
    gemm_k<64, 16, 64, 64, 64, 192, false, true, false><<<G192B, 256, 0, stream>>>(
        S2, wT_sg, bg_stem, nullptr, stpart, S2);
    bnpar_k<<<1, 256, 0, stream>>>(stpart, g_stem, b_stem, st0, G192B);

    // ---- c1 + c2 (BN fused into packed projection, shared edge pass) ----
    gemm_k<128, 32, 64, 64, 128, 128, true, false, true><<<G128B, 256, 0, stream>>>(
        S2, wT_12, bAB, st0, nullptr, y12);                // y12 bf16
    edge2_k<<<N4, 256, 0, stream>>>((const unsigned*)y12, (float2*)pos2, rs, csrc,
                                    wl_c1, wl_c2, S1, S3);
    gemm_k<64, 16, 64, 64, 64, 192, false, true, false><<<G192B, 256, 0, stream>>>(
        S1, wT_g1, bg_c1, nullptr, stpart, S1);
    bnpar_k<<<1, 256, 0, stream>>>(stpart, g_c1, b_c1, st1, G192B);
    gemm_k<64, 16, 64, 64, 64, 192, false, true, false><<<G192B, 256, 0, stream>>>(
        S3, wT_g2, bg_c2, nullptr, stpart, S3);
    bnpar_k<<<1, 256, 0, stream>>>(stpart, g_c2, b_c2, st2, G192B);

    // ---- reg + obj heads (input x1 = BN(S1), fused) ----
    gemm_k<5, 4, 64, 64, 8, 192, true, false, true><<<G192B, 256, 0, stream>>>(
        S1, wT_ro, bro, st1, nullptr, y_ro);               // y_ro bf16
    edge_ro_k<<<N4, 256, 0, stream>>>((const unsigned short*)y_ro, (float2*)pos2,
                                      rs, csrc, wro, aggr, aggo);

    // ---- cls head (input x2 = BN(S3), fused) ----
    gemm_k<101, 28, 64, 64, 104, 128, true, false, true><<<G128B, 256, 0, stream>>>(
        S3, wT_cp, bl_cls, st2, nullptr, y_cls);           // y_cls bf16
    edge_cls_k<<<N4, 256, 0, stream>>>((const unsigned short*)y_cls, (float2*)pos2,
                                       rs, csrc, wl_cls, aggc16);
    mfma_cls_k<<<MB, 256, 0, stream>>>(aggc16, wcg16, bg_cls, (float*)d_out);
    final_ro_k<<<NB, 256, 0, stream>>>(aggr, aggo, wg_reg, bg_reg, wg_obj, bg_obj,
                                       (float*)d_out);
}

// Round 14
// 783.584 us; speedup vs baseline: 1.3104x; 1.1562x over previous
//
#include <hip/hip_runtime.h>
#include <hip/hip_bf16.h>

#define NN 100000
#define NE 1600000
#define NCLS 101
#define EPS_BN 1e-5f
#define NINF (-__builtin_inff())
#define NBUCK 196      // ceil(NN/512)
#define BCAP 12288     // max edges/bucket
#define G128B 782      // ceil(NN/128)
#define G192B 521      // ceil(NN/192)
#define CHUNK 2048     // edges per binning block

typedef __attribute__((ext_vector_type(8))) short bf16x8;
typedef __attribute__((ext_vector_type(4))) float f32x4;

__device__ __forceinline__ int rl_i(int v, int j) {
    return __builtin_amdgcn_readlane(v, j);
}
__device__ __forceinline__ float rl_f(float v, int j) {
    return __int_as_float(__builtin_amdgcn_readlane(__float_as_int(v), j));
}
__device__ __forceinline__ float b2f(unsigned short u) {
    return __uint_as_float(((unsigned)u) << 16);
}
__device__ __forceinline__ unsigned short f2b(float v) {
    return __bfloat16_as_ushort(__float2bfloat16(v));
}

// ============================================================================
// CSR build, bucketed with block-level binning (unchanged).
// ============================================================================
__global__ __launch_bounds__(256) void bucket_k(const int* __restrict__ src,
                                                const int* __restrict__ dst,
                                                int* __restrict__ bcnt16,
                                                int* __restrict__ bstore) {
    __shared__ int vals[CHUNK];
    __shared__ int sval[CHUNK];
    __shared__ unsigned char bks[CHUNK];
    __shared__ unsigned char sbk[CHUNK];
    __shared__ int hist[256];
    __shared__ int scn[256];
    __shared__ int loff[256];
    __shared__ int cur[256];
    __shared__ int gshift[256];
    int e0 = blockIdx.x * CHUNK;
    int cnt = NE - e0;
    if (cnt > CHUNK) cnt = CHUNK;
    int t = threadIdx.x;
    hist[t] = 0;
    __syncthreads();
    for (int i = t; i < cnt; i += 256) {
        int d = dst[e0 + i], s = src[e0 + i];
        int b = d >> 9;
        vals[i] = ((d & 511) << 17) | s;
        bks[i] = (unsigned char)b;
        atomicAdd(&hist[b], 1);
    }
    __syncthreads();
    int v = hist[t];
    scn[t] = v;
    __syncthreads();
    for (int off = 1; off < 256; off <<= 1) {
        int u = (t >= off) ? scn[t - off] : 0;
        __syncthreads();
        scn[t] += u;
        __syncthreads();
    }
    loff[t] = scn[t] - v;
    cur[t] = scn[t] - v;
    if (t < NBUCK) {
        int base = (v > 0) ? atomicAdd(&bcnt16[t * 16], v) : 0;
        gshift[t] = base - loff[t];
    }
    __syncthreads();
    for (int i = t; i < cnt; i += 256) {
        int b = bks[i];
        int p = atomicAdd(&cur[b], 1);
        sval[p] = vals[i];
        sbk[p] = (unsigned char)b;
    }
    __syncthreads();
    for (int i = t; i < cnt; i += 256) {
        int b = sbk[i];
        int q = gshift[b] + i;
        if (q < BCAP) bstore[(size_t)b * BCAP + q] = sval[i];
    }
}

__global__ __launch_bounds__(256) void bscan_k(const int* __restrict__ bcnt16,
                                               int* __restrict__ bbase) {
    __shared__ int sh[256];
    int t = threadIdx.x;
    int v = (t < NBUCK) ? bcnt16[t * 16] : 0;
    sh[t] = v;
    __syncthreads();
    for (int off = 1; off < 256; off <<= 1) {
        int u = (t >= off) ? sh[t - off] : 0;
        __syncthreads();
        sh[t] += u;
        __syncthreads();
    }
    if (t < NBUCK) bbase[t] = sh[t] - v;
}

__global__ __launch_bounds__(512) void b2csr_k(const int* __restrict__ bcnt16,
                                               const int* __restrict__ bbase,
                                               const int* __restrict__ bstore,
                                               int* __restrict__ rs,
                                               int* __restrict__ csrc) {
    __shared__ int hist[512];
    __shared__ int scn[512];
    __shared__ int cur[512];
    int b = blockIdx.x;
    int t = threadIdx.x;
    int cnt = bcnt16[b * 16];
    if (cnt > BCAP) cnt = BCAP;
    int gbase = bbase[b];
    const int* bs = bstore + (size_t)b * BCAP;
    hist[t] = 0;
    __syncthreads();
    for (int i = t; i < cnt; i += 512) atomicAdd(&hist[bs[i] >> 17], 1);
    __syncthreads();
    int v = hist[t];
    scn[t] = v;
    __syncthreads();
    for (int off = 1; off < 512; off <<= 1) {
        int u = (t >= off) ? scn[t - off] : 0;
        __syncthreads();
        scn[t] += u;
        __syncthreads();
    }
    int ex = scn[t] - v;
    cur[t] = ex;
    int node = b * 512 + t;
    if (node < NN) rs[node] = gbase + ex;
    if (b == 0 && t == 0) rs[NN] = NE;
    __syncthreads();
    for (int i = t; i < cnt; i += 512) {
        int e = bs[i];
        int p = atomicAdd(&cur[e >> 17], 1);
        csrc[gbase + p] = e & 0x1FFFF;
    }
}

__global__ __launch_bounds__(256) void pos2_k(const float* __restrict__ pos,
                                              float2* __restrict__ pos2) {
    int n = blockIdx.x * 256 + threadIdx.x;
    if (n < NN) pos2[n] = make_float2(pos[n * 3], pos[n * 3 + 1]);
}

// ============================================================================
// One-shot weight packing. MFMA B-tiles: bf16 [COUT/16][16 n][64 k].
// ============================================================================
__global__ __launch_bounds__(256) void pack_all_k(
    const float* __restrict__ wl_stem, const float* __restrict__ wg_stem,
    const float* __restrict__ wl_c1, const float* __restrict__ bl_c1,
    const float* __restrict__ wl_c2, const float* __restrict__ bl_c2,
    const float* __restrict__ wg_c1, const float* __restrict__ wg_c2,
    const float* __restrict__ wl_reg, const float* __restrict__ wl_obj,
    const float* __restrict__ bl_reg, const float* __restrict__ bl_obj,
    const float* __restrict__ wl_cls, const float* __restrict__ wg_cls,
    float* __restrict__ wT_sg, float* __restrict__ wT_g1,
    float* __restrict__ wT_g2, float* __restrict__ wT_ro,
    unsigned short* __restrict__ wb_sp, unsigned short* __restrict__ wb_12,
    unsigned short* __restrict__ wb_cp, unsigned short* __restrict__ wcg16,
    float* __restrict__ bAB, float* __restrict__ wro, float* __restrict__ bro) {
    int u = blockIdx.x * 256 + threadIdx.x;
    if (u < 4096) { int j = u >> 6, c = u & 63; wT_sg[u] = wg_stem[c * 64 + j]; return; }
    u -= 4096;
    if (u < 4096) { int j = u >> 6, c = u & 63; wT_g1[u] = wg_c1[c * 64 + j]; return; }
    u -= 4096;
    if (u < 4096) { int j = u >> 6, c = u & 63; wT_g2[u] = wg_c2[c * 64 + j]; return; }
    u -= 4096;
    if (u < 1024) { int j = u >> 4, c = u & 15;
        wT_ro[u] = (c < 4) ? wl_reg[c * 66 + j] : ((c == 4) ? wl_obj[j] : 0.f); return; }
    u -= 1024;
    if (u < 4096) {   // wb_sp: cg = (u>>10)*16 + ((u>>6)&15), k = u&63
        int k = u & 63, n = (u >> 6) & 15, t2 = u >> 10;
        wb_sp[u] = f2b(wl_stem[(t2 * 16 + n) * 66 + k]);
        return;
    }
    u -= 4096;
    if (u < 8192) {   // wb_12: cg interleaved (even=c1, odd=c2)
        int k = u & 63, n = (u >> 6) & 15, t2 = u >> 10;
        int cg = t2 * 16 + n;
        wb_12[u] = f2b(((cg & 1) ? wl_c2 : wl_c1)[(cg >> 1) * 66 + k]);
        return;
    }
    u -= 8192;
    if (u < 8192) {   // wb_cp: cg 0..127, zero-padded past 101
        int k = u & 63, n = (u >> 6) & 15, t2 = u >> 10;
        int cg = t2 * 16 + n;
        wb_cp[u] = (cg < NCLS) ? f2b(wl_cls[cg * 66 + k]) : (unsigned short)0;
        return;
    }
    u -= 8192;
    if (u < 14336) {   // wcg16[t][n][128 k] for final cls mfma
        int k = u & 127;
        int n = (u >> 7) & 15;
        int t2 = u >> 11;
        int ng = t2 * 16 + n;
        float v = (ng < NCLS && k < NCLS) ? wg_cls[ng * NCLS + k] : 0.f;
        wcg16[u] = f2b(v);
        return;
    }
    u -= 14336;
    if (u < 128) { bAB[u] = (u & 1) ? bl_c2[u >> 1] : bl_c1[u >> 1]; return; }
    u -= 128;
    if (u < 330) { int cc = u / 66, j = u - cc * 66;
        wro[u] = (cc < 4) ? wl_reg[u] : wl_obj[j]; return; }
    u -= 330;
    if (u < 5) bro[u] = (u < 4) ? bl_reg[u] : bl_obj[0];
}

// ============================================================================
// MFMA projection GEMM: out[n][c] (bf16) = in[n][:64] @ W^T + b, K=64.
// No LDS, no barrier. Wave per 16-row strip (64 rows/block). A fragments
// loaded per-lane from global fp32 (BN+ReLU fused), converted to bf16.
// B pre-packed bf16 [COUT/16][16 n][64 k]. ILV: interleaved output col
// mapping ushort_idx = (cg&63)*2 + (cg>>6), writing zeros for cg >= NC.
// ============================================================================
template <int COUT, int NC, int IS, int OS, bool BNF, bool ILV>
__global__ __launch_bounds__(256) void mfma_lin_k(
    const float* __restrict__ in,
    const unsigned short* __restrict__ wb,
    const float* __restrict__ bias,
    const float* __restrict__ st,
    unsigned short* __restrict__ out) {
    int wid = __builtin_amdgcn_readfirstlane(threadIdx.x >> 6);
    int lane = threadIdx.x & 63;
    int quad = lane >> 4, l16 = lane & 15;
    int rbase = blockIdx.x * 64 + wid * 16;
    int row = rbase + l16;
    int rcl = (row < NN) ? row : (NN - 1);
    const float* arow = in + (size_t)rcl * IS + quad * 8;
    bf16x8 a[2];
#pragma unroll
    for (int kc = 0; kc < 2; ++kc) {
        float4 v0 = *(const float4*)(arow + kc * 32);
        float4 v1 = *(const float4*)(arow + kc * 32 + 4);
        float vv[8] = {v0.x, v0.y, v0.z, v0.w, v1.x, v1.y, v1.z, v1.w};
        bf16x8 av;
#pragma unroll
        for (int j = 0; j < 8; ++j) {
            float v = vv[j];
            if constexpr (BNF) {
                int col = kc * 32 + quad * 8 + j;
                v = fmaxf(fmaf(v, st[128 + col], st[192 + col]), 0.f);
            }
            av[j] = (short)f2b(v);
        }
        a[kc] = av;
    }
#pragma unroll
    for (int t = 0; t < COUT / 16; ++t) {
        const unsigned short* brow = wb + t * 1024 + l16 * 64 + quad * 8;
        f32x4 acc = {0.f, 0.f, 0.f, 0.f};
        acc = __builtin_amdgcn_mfma_f32_16x16x32_bf16(
            a[0], *(const bf16x8*)brow, acc, 0, 0, 0);
        acc = __builtin_amdgcn_mfma_f32_16x16x32_bf16(
            a[1], *(const bf16x8*)(brow + 32), acc, 0, 0, 0);
        int cg = t * 16 + l16;
        float bv = (cg < NC) ? bias[cg] : 0.f;
#pragma unroll
        for (int r = 0; r < 4; ++r) {
            int rg = rbase + quad * 4 + r;
            if (rg < NN) {
                if constexpr (ILV) {
                    unsigned short hv = (cg < NC) ? f2b(acc[r] + bv) : (unsigned short)0;
                    out[(size_t)rg * OS + (cg & 63) * 2 + (cg >> 6)] = hv;
                } else {
                    if (cg < NC) out[(size_t)rg * OS + cg] = f2b(acc[r] + bv);
                }
            }
        }
    }
}

// ============================================================================
// Vector node GEMM (kept for BN-stats producers + tiny ro head).
// ============================================================================
template <int COUT, int CPW, int K, int IS, int OS, int MT, bool BNF, bool STOUT,
          bool BOUT>
__global__ __launch_bounds__(256) void gemm_k(const float* __restrict__ in,
                                              const float* __restrict__ wT,
                                              const float* __restrict__ bias,
                                              const float* __restrict__ st,
                                              float* __restrict__ stpart,
                                              float* __restrict__ out) {
    constexpr int CP = 4 * CPW;
    constexpr int RM = MT / 64;
    constexpr int XR = MT + 1;
    __shared__ __align__(16) float xs[K * XR];
    __shared__ __align__(16) float wsh[K * CP];
    int base = blockIdx.x * MT;
    for (int p = threadIdx.x; p < K * CP / 4; p += 256)
        ((float4*)wsh)[p] = ((const float4*)wT)[p];
    for (int p = threadIdx.x; p < MT * K; p += 256) {
        int n = p / K, j = p - n * K;
        float v = (base + n < NN) ? in[(size_t)(base + n) * IS + j] : 0.f;
        if constexpr (BNF) v = fmaxf(fmaf(v, st[128 + j], st[192 + j]), 0.f);
        xs[j * XR + n] = v;
    }
    __syncthreads();
    int wid = __builtin_amdgcn_readfirstlane(threadIdx.x >> 6);
    int lane = threadIdx.x & 63;
    int c0 = wid * CPW;
    if (c0 >= COUT) return;
    float acc[RM][CPW];
#pragma unroll
    for (int k = 0; k < CPW; ++k) {
        float bv = (c0 + k < COUT) ? bias[c0 + k] : 0.f;
#pragma unroll
        for (int r = 0; r < RM; ++r) acc[r][k] = bv;
    }
    for (int j = 0; j < K; ++j) {
        float a[RM];
#pragma unroll
        for (int r = 0; r < RM; ++r) a[r] = xs[j * XR + 64 * r + lane];
#pragma unroll
        for (int q = 0; q < CPW / 4; ++q) {
            float4 wv = *(const float4*)&wsh[j * CP + c0 + 4 * q];
#pragma unroll
            for (int r = 0; r < RM; ++r) {
                acc[r][4 * q + 0] = fmaf(a[r], wv.x, acc[r][4 * q + 0]);
                acc[r][4 * q + 1] = fmaf(a[r], wv.y, acc[r][4 * q + 1]);
                acc[r][4 * q + 2] = fmaf(a[r], wv.z, acc[r][4 * q + 2]);
                acc[r][4 * q + 3] = fmaf(a[r], wv.w, acc[r][4 * q + 3]);
            }
        }
    }
#pragma unroll
    for (int r = 0; r < RM; ++r) {
        int node = base + 64 * r + lane;
        if (node < NN) {
#pragma unroll
            for (int k = 0; k < CPW; ++k) {
                if (c0 + k < COUT) {
                    if constexpr (BOUT) {
                        __hip_bfloat16* ob = (__hip_bfloat16*)out;
                        ob[(size_t)node * OS + c0 + k] = __float2bfloat16(acc[r][k]);
                    } else {
                        out[(size_t)node * OS + c0 + k] = acc[r][k];
                    }
                }
            }
        }
    }
    if constexpr (STOUT) {
        float* sp = stpart + (size_t)blockIdx.x * 128;
#pragma unroll
        for (int k = 0; k < CPW; ++k) {
            if (c0 + k < COUT) {
                float s = 0.f, q = 0.f;
#pragma unroll
                for (int r = 0; r < RM; ++r) {
                    float v = (base + 64 * r + lane < NN) ? acc[r][k] : 0.f;
                    s += v;
                    q = fmaf(v, v, q);
                }
#pragma unroll
                for (int off = 1; off < 64; off <<= 1) {
                    s += __shfl_xor(s, off, 64);
                    q += __shfl_xor(q, off, 64);
                }
                if (lane == 0) {
                    sp[c0 + k] = s;
                    sp[64 + c0 + k] = q;
                }
            }
        }
    }
}

// ============================================================================
// MFMA final cls GEMM (unchanged from R13).
// ============================================================================
__global__ __launch_bounds__(256) void mfma_cls_k(
    const unsigned short* __restrict__ aggc16,
    const unsigned short* __restrict__ wcg16,
    const float* __restrict__ bgc,
    float* __restrict__ out) {
    int wid = __builtin_amdgcn_readfirstlane(threadIdx.x >> 6);
    int lane = threadIdx.x & 63;
    int quad = lane >> 4;
    int l16 = lane & 15;
    int mbase = blockIdx.x * 64 + wid * 16;
    bf16x8 a[4];
    const unsigned short* arow = aggc16 + (size_t)(mbase + l16) * 128 + quad * 8;
#pragma unroll
    for (int kc = 0; kc < 4; ++kc)
        a[kc] = *(const bf16x8*)(arow + kc * 32);
    for (int t = 0; t < 7; ++t) {
        const unsigned short* brow = wcg16 + t * 2048 + l16 * 128 + quad * 8;
        f32x4 acc = {0.f, 0.f, 0.f, 0.f};
#pragma unroll
        for (int kc = 0; kc < 4; ++kc) {
            bf16x8 b = *(const bf16x8*)(brow + kc * 32);
            acc = __builtin_amdgcn_mfma_f32_16x16x32_bf16(a[kc], b, acc, 0, 0, 0);
        }
        int cg = t * 16 + l16;
        if (cg < NCLS) {
            float bv = bgc[cg];
#pragma unroll
            for (int r = 0; r < 4; ++r) {
                int rg = mbase + quad * 4 + r;
                if (rg < NN) out[(size_t)rg * NCLS + cg] = acc[r] + bv;
            }
        }
    }
}

// reduce per-block partials -> BN scale/shift.
__global__ __launch_bounds__(256) void bnpar_k(const float* __restrict__ stpart,
                                               const float* __restrict__ g,
                                               const float* __restrict__ b,
                                               float* __restrict__ st, int nparts) {
    __shared__ float sS[4][64], sQ[4][64];
    int c = threadIdx.x & 63;
    int part = threadIdx.x >> 6;
    float s = 0.f, q = 0.f;
    for (int i = part; i < nparts; i += 4) {
        s += stpart[(size_t)i * 128 + c];
        q += stpart[(size_t)i * 128 + 64 + c];
    }
    sS[part][c] = s;
    sQ[part][c] = q;
    __syncthreads();
    if (part == 0) {
        s = sS[0][c] + sS[1][c] + sS[2][c] + sS[3][c];
        q = sQ[0][c] + sQ[1][c] + sQ[2][c] + sQ[3][c];
        float mu = s * (1.0f / NN);
        float var = q * (1.0f / NN) - mu * mu;
        float sc = g[c] * rsqrtf(var + EPS_BN);
        st[128 + c] = sc;
        st[192 + c] = b[c] - mu * sc;
    }
}

// ============================================================================
// Edge segment-max over CSR, bf16 payloads.
// ============================================================================
__global__ __launch_bounds__(256) void edge1_k(const unsigned short* __restrict__ y,  // bf16, stride 64
                                               const float2* __restrict__ pos2,
                                               const int* __restrict__ rs,
                                               const int* __restrict__ csrc,
                                               const float* __restrict__ wl,  // (64,66)
                                               float* __restrict__ agg) {
    int wid = __builtin_amdgcn_readfirstlane(threadIdx.x >> 6);
    int lane = threadIdx.x & 63;
    int node = blockIdx.x * 4 + wid;
    if (node >= NN) return;
    float wp0 = wl[lane * 66 + 64], wp1 = wl[lane * 66 + 65];
    float2 pd = pos2[node];
    int i0 = rs[node], i1 = rs[node + 1];
    float acc = NINF;
    for (int ib = i0; ib < i1; ib += 64) {
        int m = i1 - ib;
        if (m > 64) m = 64;
        int t = ib + lane;
        int idx = (t < i1) ? csrc[t] : 0;
        float2 pp = pos2[idx];
        float ppx = pp.x, ppy = pp.y;
        int j = 0;
        for (; j + 8 <= m; j += 8) {
            float v[8];
#pragma unroll
            for (int q = 0; q < 8; ++q)
                v[q] = b2f(y[(size_t)rl_i(idx, j + q) * 64 + lane]);
#pragma unroll
            for (int q = 0; q < 8; ++q) {
                float dx = rl_f(ppx, j + q) - pd.x, dy = rl_f(ppy, j + q) - pd.y;
                acc = fmaxf(acc, fmaf(dy, wp1, fmaf(dx, wp0, v[q])));
            }
        }
        for (; j < m; ++j) {
            float v = b2f(y[(size_t)rl_i(idx, j) * 64 + lane]);
            acc = fmaxf(acc, fmaf(rl_f(ppy, j) - pd.y, wp1,
                                  fmaf(rl_f(ppx, j) - pd.x, wp0, v)));
        }
    }
    agg[(size_t)node * 64 + lane] = fmaxf(acc, 0.0f);
}

// y12: bf16 [n][64]{c1,c2} pairs -> one uint per lane
__global__ __launch_bounds__(256) void edge2_k(const unsigned* __restrict__ y12,
                                               const float2* __restrict__ pos2,
                                               const int* __restrict__ rs,
                                               const int* __restrict__ csrc,
                                               const float* __restrict__ wlA,
                                               const float* __restrict__ wlB,
                                               float* __restrict__ a1,
                                               float* __restrict__ a2) {
    int wid = __builtin_amdgcn_readfirstlane(threadIdx.x >> 6);
    int lane = threadIdx.x & 63;
    int node = blockIdx.x * 4 + wid;
    if (node >= NN) return;
    float wa0 = wlA[lane * 66 + 64], wa1 = wlA[lane * 66 + 65];
    float wb0 = wlB[lane * 66 + 64], wb1 = wlB[lane * 66 + 65];
    float2 pd = pos2[node];
    int i0 = rs[node], i1 = rs[node + 1];
    float accA = NINF, accB = NINF;
    for (int ib = i0; ib < i1; ib += 64) {
        int m = i1 - ib;
        if (m > 64) m = 64;
        int t = ib + lane;
        int idx = (t < i1) ? csrc[t] : 0;
        float2 pp = pos2[idx];
        float ppx = pp.x, ppy = pp.y;
        int j = 0;
        for (; j + 8 <= m; j += 8) {
            unsigned w[8];
#pragma unroll
            for (int q = 0; q < 8; ++q)
                w[q] = y12[(size_t)rl_i(idx, j + q) * 64 + lane];
#pragma unroll
            for (int q = 0; q < 8; ++q) {
                float dx = rl_f(ppx, j + q) - pd.x, dy = rl_f(ppy, j + q) - pd.y;
                accA = fmaxf(accA, fmaf(dy, wa1, fmaf(dx, wa0,
                                        b2f((unsigned short)w[q]))));
                accB = fmaxf(accB, fmaf(dy, wb1, fmaf(dx, wb0,
                                        b2f((unsigned short)(w[q] >> 16)))));
            }
        }
        for (; j < m; ++j) {
            unsigned w = y12[(size_t)rl_i(idx, j) * 64 + lane];
            float dx = rl_f(ppx, j) - pd.x, dy = rl_f(ppy, j) - pd.y;
            accA = fmaxf(accA, fmaf(dy, wa1, fmaf(dx, wa0, b2f((unsigned short)w))));
            accB = fmaxf(accB, fmaf(dy, wb1, fmaf(dx, wb0,
                                    b2f((unsigned short)(w >> 16)))));
        }
    }
    a1[(size_t)node * 64 + lane] = fmaxf(accA, 0.0f);
    a2[(size_t)node * 64 + lane] = fmaxf(accB, 0.0f);
}

// cls: wave per node; y_cls interleaved [n][64] dwords = (col c lo, col c+64 hi).
// One dword gather per edge per lane. Writes aggb [node][128] bf16 (pad zeroed).
__global__ __launch_bounds__(256) void edge_cls_k(const unsigned* __restrict__ y32,
                                                  const float2* __restrict__ pos2,
                                                  const int* __restrict__ rs,
                                                  const int* __restrict__ csrc,
                                                  const float* __restrict__ wl,  // (101,66)
                                                  unsigned short* __restrict__ aggb) {
    int wid = __builtin_amdgcn_readfirstlane(threadIdx.x >> 6);
    int lane = threadIdx.x & 63;
    int node = blockIdx.x * 4 + wid;
    if (node >= NN) return;
    int chi = (lane + 64 < NCLS) ? (lane + 64) : (NCLS - 1);
    float wa0 = wl[lane * 66 + 64], wa1 = wl[lane * 66 + 65];
    float wb0 = wl[chi * 66 + 64], wb1 = wl[chi * 66 + 65];
    float2 pd = pos2[node];
    int i0 = rs[node], i1 = rs[node + 1];
    float accA = NINF, accB = NINF;
    for (int ib = i0; ib < i1; ib += 64) {
        int m = i1 - ib;
        if (m > 64) m = 64;
        int t = ib + lane;
        int idx = (t < i1) ? csrc[t] : 0;
        float2 pp = pos2[idx];
        float ppx = pp.x, ppy = pp.y;
        int j = 0;
        for (; j + 8 <= m; j += 8) {
            unsigned w[8];
#pragma unroll
            for (int q = 0; q < 8; ++q)
                w[q] = y32[(size_t)rl_i(idx, j + q) * 64 + lane];
#pragma unroll
            for (int q = 0; q < 8; ++q) {
                float dx = rl_f(ppx, j + q) - pd.x, dy = rl_f(ppy, j + q) - pd.y;
                accA = fmaxf(accA, fmaf(dy, wa1, fmaf(dx, wa0,
                                        b2f((unsigned short)w[q]))));
                accB = fmaxf(accB, fmaf(dy, wb1, fmaf(dx, wb0,
                                        b2f((unsigned short)(w[q] >> 16)))));
            }
        }
        for (; j < m; ++j) {
            unsigned w = y32[(size_t)rl_i(idx, j) * 64 + lane];
            float dx = rl_f(ppx, j) - pd.x, dy = rl_f(ppy, j) - pd.y;
            accA = fmaxf(accA, fmaf(dy, wa1, fmaf(dx, wa0, b2f((unsigned short)w))));
            accB = fmaxf(accB, fmaf(dy, wb1, fmaf(dx, wb0,
                                    b2f((unsigned short)(w >> 16)))));
        }
    }
    aggb[(size_t)node * 128 + lane] = f2b(fmaxf(accA, 0.0f));
    unsigned short hb = (lane + 64 < NCLS) ? f2b(fmaxf(accB, 0.0f)) : (unsigned short)0;
    aggb[(size_t)node * 128 + 64 + lane] = hb;
}

// reg+obj: 5 bf16 channels packed stride 8; wave = 8 edge-slots x 8 ch-slots
__global__ __launch_bounds__(256) void edge_ro_k(const unsigned short* __restrict__ y,  // bf16, stride 8
                                                 const float2* __restrict__ pos2,
                                                 const int* __restrict__ rs,
                                                 const int* __restrict__ csrc,
                                                 const float* __restrict__ wro,  // (5,66)
                                                 float* __restrict__ aggr,
                                                 float* __restrict__ aggo) {
    int wid = __builtin_amdgcn_readfirstlane(threadIdx.x >> 6);
    int lane = threadIdx.x & 63;
    int node = blockIdx.x * 4 + wid;
    if (node >= NN) return;
    int k = lane >> 3, c = lane & 7;
    int cc = (c < 5) ? c : 4;
    float wp0 = wro[cc * 66 + 64], wp1 = wro[cc * 66 + 65];
    float2 pd = pos2[node];
    int i0 = rs[node], i1 = rs[node + 1];
    float acc = NINF;
    for (int i = i0 + k; i < i1; i += 8) {
        int s = csrc[i];
        float2 p = pos2[s];
        float v = b2f(y[(size_t)s * 8 + cc]);
        acc = fmaxf(acc, fmaf(p.y - pd.y, wp1, fmaf(p.x - pd.x, wp0, v)));
    }
    acc = fmaxf(acc, __shfl_xor(acc, 8, 64));
    acc = fmaxf(acc, __shfl_xor(acc, 16, 64));
    acc = fmaxf(acc, __shfl_xor(acc, 32, 64));
    acc = fmaxf(acc, 0.0f);
    if (lane < 5) {
        if (lane < 4) aggr[(size_t)node * 4 + lane] = acc;
        else          aggo[node] = acc;
    }
}

__global__ __launch_bounds__(256) void final_ro_k(const float* __restrict__ aggr,
                                                  const float* __restrict__ aggo,
                                                  const float* __restrict__ wgr,
                                                  const float* __restrict__ bgr,
                                                  const float* __restrict__ wgo,
                                                  const float* __restrict__ bgo,
                                                  float* __restrict__ out) {
    int n = blockIdx.x * 256 + threadIdx.x;
    if (n >= NN) return;
    float a0 = aggr[(size_t)n * 4 + 0], a1 = aggr[(size_t)n * 4 + 1];
    float a2 = aggr[(size_t)n * 4 + 2], a3 = aggr[(size_t)n * 4 + 3];
    float* reg = out + (size_t)NN * NCLS;
    float* obj = reg + (size_t)NN * 4;
#pragma unroll
    for (int k = 0; k < 4; ++k) {
        float acc = bgr[k];
        acc = fmaf(a0, wgr[k * 4 + 0], acc);
        acc = fmaf(a1, wgr[k * 4 + 1], acc);
        acc = fmaf(a2, wgr[k * 4 + 2], acc);
        acc = fmaf(a3, wgr[k * 4 + 3], acc);
        reg[(size_t)n * 4 + k] = acc;
    }
    obj[n] = fmaf(aggo[n], wgo[0], bgo[0]);
}

// ============================================================================
extern "C" void kernel_launch(void* const* d_in, const int* in_sizes, int n_in,
                              void* d_out, int out_size, void* d_ws, size_t ws_size,
                              hipStream_t stream) {
    const float* x   = (const float*)d_in[0];
    const float* pos = (const float*)d_in[1];
    const int* ei    = (const int*)d_in[2];
    const int* src = ei;
    const int* dst = ei + NE;
    const float* wl_stem = (const float*)d_in[3];
    const float* bl_stem = (const float*)d_in[4];
    const float* wg_stem = (const float*)d_in[5];
    const float* bg_stem = (const float*)d_in[6];
    const float* g_stem  = (const float*)d_in[7];
    const float* b_stem  = (const float*)d_in[8];
    const float* wl_c1 = (const float*)d_in[9];
    const float* bl_c1 = (const float*)d_in[10];
    const float* wg_c1 = (const float*)d_in[11];
    const float* bg_c1 = (const float*)d_in[12];
    const float* g_c1  = (const float*)d_in[13];
    const float* b_c1  = (const float*)d_in[14];
    const float* wl_c2 = (const float*)d_in[15];
    const float* bl_c2 = (const float*)d_in[16];
    const float* wg_c2 = (const float*)d_in[17];
    const float* bg_c2 = (const float*)d_in[18];
    const float* g_c2  = (const float*)d_in[19];
    const float* b_c2  = (const float*)d_in[20];
    const float* wl_reg = (const float*)d_in[21];
    const float* bl_reg = (const float*)d_in[22];
    const float* wg_reg = (const float*)d_in[23];
    const float* bg_reg = (const float*)d_in[24];
    const float* wl_cls = (const float*)d_in[25];
    const float* bl_cls = (const float*)d_in[26];
    const float* wg_cls = (const float*)d_in[27];
    const float* bg_cls = (const float*)d_in[28];
    const float* wl_obj = (const float*)d_in[29];
    const float* bl_obj = (const float*)d_in[30];
    const float* wg_obj = (const float*)d_in[31];
    const float* bg_obj = (const float*)d_in[32];

    float* ws = (float*)d_ws;
    // Arena: S0[N*128] | S1[N*64] | S2[N*64] | S3[N*64] | ints/smalls
    float* S0 = ws;
    float* S1 = S0 + (size_t)NN * 128;
    float* S2 = S1 + (size_t)NN * 64;
    float* S3 = S2 + (size_t)NN * 64;
    float* y12   = S0;       // bf16 [n][128]
    float* y_cls = S0;       // bf16 [n][128] interleaved dwords
    unsigned short* aggc16 = (unsigned short*)S1;   // bf16 [n][128]
    int*   bstore = (int*)S0;                     // NBUCK*BCAP ints
    int*   rs   = (int*)(S3 + (size_t)NN * 64);   // NN+1 (padded to 100016)
    int*   csrc = rs + 100016;                    // NE
    float* pos2 = (float*)(csrc + NE);            // NN float2
    float* y_ro = pos2 + (size_t)NN * 2;          // bf16 [n][8] (slot sized fp32)
    float* aggr = y_ro + (size_t)NN * 8;          // NN*4
    float* aggo = aggr + (size_t)NN * 4;          // NN
    float* st   = aggo + NN;                      // 3*256 (params at [128..255])
    float* st0 = st, *st1 = st + 256, *st2 = st + 512;
    float* wro = st + 768;                        // 336
    float* bro = wro + 336;                       // 16
    int*   bcnt16 = (int*)(bro + 16);             // NBUCK*16 (line-padded)
    int*   bbase  = bcnt16 + NBUCK * 16;          // 256
    float* wT_sg = (float*)(bbase + 256);         // [64][64] fp32
    float* wT_g1 = wT_sg + 4096;
    float* wT_g2 = wT_g1 + 4096;
    float* wT_ro = wT_g2 + 4096;                  // [64][16]
    unsigned short* wb_sp = (unsigned short*)(wT_ro + 1024);  // 4096 bf16
    unsigned short* wb_12 = wb_sp + 4096;                     // 8192 bf16
    unsigned short* wb_cp = wb_12 + 8192;                     // 8192 bf16
    unsigned short* wcg16 = wb_cp + 8192;                     // 14336 bf16
    float* bAB   = (float*)(wcg16 + 14336);       // 128
    float* stpart = bAB + 128;                    // partials (400 KB)

    hipMemsetAsync(bcnt16, 0, NBUCK * 16 * sizeof(int), stream);

    const int NB = (NN + 255) / 256;      // 391
    const int N4 = (NN + 3) / 4;          // 25000
    const int CB = (NE + CHUNK - 1) / CHUNK;  // 782 binning blocks
    const int MB = (NN + 63) / 64;        // 1563 mfma blocks

    // ---- packing + CSR build + pos2 ----
    pack_all_k<<<190, 256, 0, stream>>>(wl_stem, wg_stem, wl_c1, bl_c1, wl_c2,
                                        bl_c2, wg_c1, wg_c2, wl_reg, wl_obj,
                                        bl_reg, bl_obj, wl_cls, wg_cls,
                                        wT_sg, wT_g1, wT_g2, wT_ro,
                                        wb_sp, wb_12, wb_cp, wcg16,
                                        bAB, wro, bro);
    pos2_k<<<NB, 256, 0, stream>>>(pos, (float2*)pos2);
    bucket_k<<<CB, 256, 0, stream>>>(src, dst, bcnt16, bstore);
    bscan_k<<<1, 256, 0, stream>>>(bcnt16, bbase);
    b2csr_k<<<NBUCK, 512, 0, stream>>>(bcnt16, bbase, bstore, rs, csrc);

    // ---- stem ----
    mfma_lin_k<64, 64, 64, 64, false, false><<<MB, 256, 0, stream>>>(
        x, wb_sp, bl_stem, nullptr, (unsigned short*)S1);   // y_stem bf16 in S1
    edge1_k<<<N4, 256, 0, stream>>>((const unsigned short*)S1, (float2*)pos2, rs,
                                    csrc, wl_stem, S2);
    gemm_k<64, 16, 64, 64, 64, 192, false, true, false><<<G192B, 256, 0, stream>>>(
        S2, wT_sg, bg_stem, nullptr, stpart, S2);
    bnpar_k<<<1, 256, 0, stream>>>(stpart, g_stem, b_stem, st0, G192B);

    // ---- c1 + c2 (BN fused into packed MFMA projection, shared edge pass) ----
    mfma_lin_k<128, 128, 64, 128, true, false><<<MB, 256, 0, stream>>>(
        S2, wb_12, bAB, st0, (unsigned short*)y12);         // y12 bf16 pairs
    edge2_k<<<N4, 256, 0, stream>>>((const unsigned*)y12, (float2*)pos2, rs, csrc,
                                    wl_c1, wl_c2, S1, S3);
    gemm_k<64, 16, 64, 64, 64, 192, false, true, false><<<G192B, 256, 0, stream>>>(
        S1, wT_g1, bg_c1, nullptr, stpart, S1);
    bnpar_k<<<1, 256, 0, stream>>>(stpart, g_c1, b_c1, st1, G192B);
    gemm_k<64, 16, 64, 64, 64, 192, false, true, false><<<G192B, 256, 0, stream>>>(
        S3, wT_g2, bg_c2, nullptr, stpart, S3);
    bnpar_k<<<1, 256, 0, stream>>>(stpart, g_c2, b_c2, st2, G192B);

    // ---- reg + obj heads (input x1 = BN(S1), fused) ----
    gemm_k<5, 4, 64, 64, 8, 192, true, false, true><<<G192B, 256, 0, stream>>>(
        S1, wT_ro, bro, st1, nullptr, y_ro);               // y_ro bf16
    edge_ro_k<<<N4, 256, 0, stream>>>((const unsigned short*)y_ro, (float2*)pos2,
                                      rs, csrc, wro, aggr, aggo);

    // ---- cls head (input x2 = BN(S3), fused; interleaved y_cls) ----
    mfma_lin_k<128, NCLS, 64, 128, true, true><<<MB, 256, 0, stream>>>(
        S3, wb_cp, bl_cls, st2, (unsigned short*)y_cls);
    edge_cls_k<<<N4, 256, 0, stream>>>((const unsigned*)y_cls, (float2*)pos2,
                                       rs, csrc, wl_cls, aggc16);
    mfma_cls_k<<<MB, 256, 0, stream>>>(aggc16, wcg16, bg_cls, (float*)d_out);
    final_ro_k<<<NB, 256, 0, stream>>>(aggr, aggo, wg_reg, bg_reg, wg_obj, bg_obj,
                                       (float*)d_out);
}

// Round 15
// 653.693 us; speedup vs baseline: 1.5708x; 1.1987x over previous
//
#include <hip/hip_runtime.h>
#include <hip/hip_bf16.h>

#define NN 100000
#define NE 1600000
#define NCLS 101
#define EPS_BN 1e-5f
#define NINF (-__builtin_inff())
#define NBUCK 196      // ceil(NN/512)
#define BCAP 12288     // max edges/bucket
#define G192B 521      // ceil(NN/192)
#define MBK 1563       // ceil(NN/64) mfma blocks
#define CHUNK 2048     // edges per binning block

typedef __attribute__((ext_vector_type(8))) short bf16x8;
typedef __attribute__((ext_vector_type(4))) float f32x4;

__device__ __forceinline__ int rl_i(int v, int j) {
    return __builtin_amdgcn_readlane(v, j);
}
__device__ __forceinline__ float rl_f(float v, int j) {
    return __int_as_float(__builtin_amdgcn_readlane(__float_as_int(v), j));
}
__device__ __forceinline__ float b2f(unsigned short u) {
    return __uint_as_float(((unsigned)u) << 16);
}
__device__ __forceinline__ unsigned short f2b(float v) {
    return __bfloat16_as_ushort(__float2bfloat16(v));
}

// ============================================================================
// CSR build, bucketed with block-level binning (unchanged).
// ============================================================================
__global__ __launch_bounds__(256) void bucket_k(const int* __restrict__ src,
                                                const int* __restrict__ dst,
                                                int* __restrict__ bcnt16,
                                                int* __restrict__ bstore) {
    __shared__ int vals[CHUNK];
    __shared__ int sval[CHUNK];
    __shared__ unsigned char bks[CHUNK];
    __shared__ unsigned char sbk[CHUNK];
    __shared__ int hist[256];
    __shared__ int scn[256];
    __shared__ int loff[256];
    __shared__ int cur[256];
    __shared__ int gshift[256];
    int e0 = blockIdx.x * CHUNK;
    int cnt = NE - e0;
    if (cnt > CHUNK) cnt = CHUNK;
    int t = threadIdx.x;
    hist[t] = 0;
    __syncthreads();
    for (int i = t; i < cnt; i += 256) {
        int d = dst[e0 + i], s = src[e0 + i];
        int b = d >> 9;
        vals[i] = ((d & 511) << 17) | s;
        bks[i] = (unsigned char)b;
        atomicAdd(&hist[b], 1);
    }
    __syncthreads();
    int v = hist[t];
    scn[t] = v;
    __syncthreads();
    for (int off = 1; off < 256; off <<= 1) {
        int u = (t >= off) ? scn[t - off] : 0;
        __syncthreads();
        scn[t] += u;
        __syncthreads();
    }
    loff[t] = scn[t] - v;
    cur[t] = scn[t] - v;
    if (t < NBUCK) {
        int base = (v > 0) ? atomicAdd(&bcnt16[t * 16], v) : 0;
        gshift[t] = base - loff[t];
    }
    __syncthreads();
    for (int i = t; i < cnt; i += 256) {
        int b = bks[i];
        int p = atomicAdd(&cur[b], 1);
        sval[p] = vals[i];
        sbk[p] = (unsigned char)b;
    }
    __syncthreads();
    for (int i = t; i < cnt; i += 256) {
        int b = sbk[i];
        int q = gshift[b] + i;
        if (q < BCAP) bstore[(size_t)b * BCAP + q] = sval[i];
    }
}

__global__ __launch_bounds__(256) void bscan_k(const int* __restrict__ bcnt16,
                                               int* __restrict__ bbase) {
    __shared__ int sh[256];
    int t = threadIdx.x;
    int v = (t < NBUCK) ? bcnt16[t * 16] : 0;
    sh[t] = v;
    __syncthreads();
    for (int off = 1; off < 256; off <<= 1) {
        int u = (t >= off) ? sh[t - off] : 0;
        __syncthreads();
        sh[t] += u;
        __syncthreads();
    }
    if (t < NBUCK) bbase[t] = sh[t] - v;
}

__global__ __launch_bounds__(512) void b2csr_k(const int* __restrict__ bcnt16,
                                               const int* __restrict__ bbase,
                                               const int* __restrict__ bstore,
                                               int* __restrict__ rs,
                                               int* __restrict__ csrc) {
    __shared__ int hist[512];
    __shared__ int scn[512];
    __shared__ int cur[512];
    int b = blockIdx.x;
    int t = threadIdx.x;
    int cnt = bcnt16[b * 16];
    if (cnt > BCAP) cnt = BCAP;
    int gbase = bbase[b];
    const int* bs = bstore + (size_t)b * BCAP;
    hist[t] = 0;
    __syncthreads();
    for (int i = t; i < cnt; i += 512) atomicAdd(&hist[bs[i] >> 17], 1);
    __syncthreads();
    int v = hist[t];
    scn[t] = v;
    __syncthreads();
    for (int off = 1; off < 512; off <<= 1) {
        int u = (t >= off) ? scn[t - off] : 0;
        __syncthreads();
        scn[t] += u;
        __syncthreads();
    }
    int ex = scn[t] - v;
    cur[t] = ex;
    int node = b * 512 + t;
    if (node < NN) rs[node] = gbase + ex;
    if (b == 0 && t == 0) rs[NN] = NE;
    __syncthreads();
    for (int i = t; i < cnt; i += 512) {
        int e = bs[i];
        int p = atomicAdd(&cur[e >> 17], 1);
        csrc[gbase + p] = e & 0x1FFFF;
    }
}

__global__ __launch_bounds__(256) void pos2_k(const float* __restrict__ pos,
                                              float2* __restrict__ pos2) {
    int n = blockIdx.x * 256 + threadIdx.x;
    if (n < NN) pos2[n] = make_float2(pos[n * 3], pos[n * 3 + 1]);
}

// ============================================================================
// One-shot weight packing. MFMA B-tiles: bf16 [COUT/16][16 n][K k].
// ============================================================================
__global__ __launch_bounds__(256) void pack_all_k(
    const float* __restrict__ wl_stem, const float* __restrict__ wg_stem,
    const float* __restrict__ wl_c1, const float* __restrict__ bl_c1,
    const float* __restrict__ wl_c2, const float* __restrict__ bl_c2,
    const float* __restrict__ wg_c1, const float* __restrict__ wg_c2,
    const float* __restrict__ wl_reg, const float* __restrict__ wl_obj,
    const float* __restrict__ bl_reg, const float* __restrict__ bl_obj,
    const float* __restrict__ wl_cls, const float* __restrict__ wg_cls,
    float* __restrict__ wT_ro,
    unsigned short* __restrict__ wb_sg, unsigned short* __restrict__ wb_g1,
    unsigned short* __restrict__ wb_g2, unsigned short* __restrict__ wb_sp,
    unsigned short* __restrict__ wb_12, unsigned short* __restrict__ wb_cp,
    unsigned short* __restrict__ wcg16,
    float* __restrict__ bAB, float* __restrict__ wro, float* __restrict__ bro) {
    int u = blockIdx.x * 256 + threadIdx.x;
    if (u < 1024) { int j = u >> 4, c = u & 15;
        wT_ro[u] = (c < 4) ? wl_reg[c * 66 + j] : ((c == 4) ? wl_obj[j] : 0.f); return; }
    u -= 1024;
    if (u < 4096) { int k = u & 63, n = (u >> 6) & 15, t2 = u >> 10;
        wb_sg[u] = f2b(wg_stem[(t2 * 16 + n) * 64 + k]); return; }
    u -= 4096;
    if (u < 4096) { int k = u & 63, n = (u >> 6) & 15, t2 = u >> 10;
        wb_g1[u] = f2b(wg_c1[(t2 * 16 + n) * 64 + k]); return; }
    u -= 4096;
    if (u < 4096) { int k = u & 63, n = (u >> 6) & 15, t2 = u >> 10;
        wb_g2[u] = f2b(wg_c2[(t2 * 16 + n) * 64 + k]); return; }
    u -= 4096;
    if (u < 4096) { int k = u & 63, n = (u >> 6) & 15, t2 = u >> 10;
        wb_sp[u] = f2b(wl_stem[(t2 * 16 + n) * 66 + k]); return; }
    u -= 4096;
    if (u < 8192) { int k = u & 63, n = (u >> 6) & 15, t2 = u >> 10;
        int cg = t2 * 16 + n;
        wb_12[u] = f2b(((cg & 1) ? wl_c2 : wl_c1)[(cg >> 1) * 66 + k]); return; }
    u -= 8192;
    if (u < 8192) { int k = u & 63, n = (u >> 6) & 15, t2 = u >> 10;
        int cg = t2 * 16 + n;
        wb_cp[u] = (cg < NCLS) ? f2b(wl_cls[cg * 66 + k]) : (unsigned short)0; return; }
    u -= 8192;
    if (u < 14336) { int k = u & 127, n = (u >> 7) & 15, t2 = u >> 11;
        int ng = t2 * 16 + n;
        float v = (ng < NCLS && k < NCLS) ? wg_cls[ng * NCLS + k] : 0.f;
        wcg16[u] = f2b(v); return; }
    u -= 14336;
    if (u < 128) { bAB[u] = (u & 1) ? bl_c2[u >> 1] : bl_c1[u >> 1]; return; }
    u -= 128;
    if (u < 330) { int cc = u / 66, j = u - cc * 66;
        wro[u] = (cc < 4) ? wl_reg[u] : wl_obj[j]; return; }
    u -= 330;
    if (u < 5) bro[u] = (u < 4) ? bl_reg[u] : bl_obj[0];
}

// ============================================================================
// MFMA projection GEMM (bf16 out), K=64. Unchanged from R14.
// ============================================================================
template <int COUT, int NC, int IS, int OS, bool BNF, bool ILV>
__global__ __launch_bounds__(256) void mfma_lin_k(
    const float* __restrict__ in,
    const unsigned short* __restrict__ wb,
    const float* __restrict__ bias,
    const float* __restrict__ st,
    unsigned short* __restrict__ out) {
    int wid = __builtin_amdgcn_readfirstlane(threadIdx.x >> 6);
    int lane = threadIdx.x & 63;
    int quad = lane >> 4, l16 = lane & 15;
    int rbase = blockIdx.x * 64 + wid * 16;
    int row = rbase + l16;
    int rcl = (row < NN) ? row : (NN - 1);
    const float* arow = in + (size_t)rcl * IS + quad * 8;
    bf16x8 a[2];
#pragma unroll
    for (int kc = 0; kc < 2; ++kc) {
        float4 v0 = *(const float4*)(arow + kc * 32);
        float4 v1 = *(const float4*)(arow + kc * 32 + 4);
        float vv[8] = {v0.x, v0.y, v0.z, v0.w, v1.x, v1.y, v1.z, v1.w};
        bf16x8 av;
#pragma unroll
        for (int j = 0; j < 8; ++j) {
            float v = vv[j];
            if constexpr (BNF) {
                int col = kc * 32 + quad * 8 + j;
                v = fmaxf(fmaf(v, st[128 + col], st[192 + col]), 0.f);
            }
            av[j] = (short)f2b(v);
        }
        a[kc] = av;
    }
#pragma unroll
    for (int t = 0; t < COUT / 16; ++t) {
        const unsigned short* brow = wb + t * 1024 + l16 * 64 + quad * 8;
        f32x4 acc = {0.f, 0.f, 0.f, 0.f};
        acc = __builtin_amdgcn_mfma_f32_16x16x32_bf16(
            a[0], *(const bf16x8*)brow, acc, 0, 0, 0);
        acc = __builtin_amdgcn_mfma_f32_16x16x32_bf16(
            a[1], *(const bf16x8*)(brow + 32), acc, 0, 0, 0);
        int cg = t * 16 + l16;
        float bv = (cg < NC) ? bias[cg] : 0.f;
#pragma unroll
        for (int r = 0; r < 4; ++r) {
            int rg = rbase + quad * 4 + r;
            if (rg < NN) {
                if constexpr (ILV) {
                    unsigned short hv = (cg < NC) ? f2b(acc[r] + bv) : (unsigned short)0;
                    out[(size_t)rg * OS + (cg & 63) * 2 + (cg >> 6)] = hv;
                } else {
                    if (cg < NC) out[(size_t)rg * OS + cg] = f2b(acc[r] + bv);
                }
            }
        }
    }
}

// ============================================================================
// MFMA wg GEMM with fused BN stats: out fp32 [n][64] (+bias); per-block
// column sum/sumsq partials -> stpart[blk][128]. In-place safe (each wave
// loads its 16-row strip fully before storing it).
// ============================================================================
__global__ __launch_bounds__(256) void mfma_stats_k(
    const float* __restrict__ in,
    const unsigned short* __restrict__ wb,   // [4][16][64] bf16
    const float* __restrict__ bias,
    float* __restrict__ out,
    float* __restrict__ stpart) {
    __shared__ float sS[4][64], sQ[4][64];
    int wid = __builtin_amdgcn_readfirstlane(threadIdx.x >> 6);
    int lane = threadIdx.x & 63;
    int quad = lane >> 4, l16 = lane & 15;
    int rbase = blockIdx.x * 64 + wid * 16;
    int row = rbase + l16;
    int rcl = (row < NN) ? row : (NN - 1);
    const float* arow = in + (size_t)rcl * 64 + quad * 8;
    bf16x8 a[2];
#pragma unroll
    for (int kc = 0; kc < 2; ++kc) {
        float4 v0 = *(const float4*)(arow + kc * 32);
        float4 v1 = *(const float4*)(arow + kc * 32 + 4);
        float vv[8] = {v0.x, v0.y, v0.z, v0.w, v1.x, v1.y, v1.z, v1.w};
        bf16x8 av;
#pragma unroll
        for (int j = 0; j < 8; ++j) av[j] = (short)f2b(vv[j]);
        a[kc] = av;
    }
#pragma unroll
    for (int t = 0; t < 4; ++t) {
        const unsigned short* brow = wb + t * 1024 + l16 * 64 + quad * 8;
        f32x4 acc = {0.f, 0.f, 0.f, 0.f};
        acc = __builtin_amdgcn_mfma_f32_16x16x32_bf16(
            a[0], *(const bf16x8*)brow, acc, 0, 0, 0);
        acc = __builtin_amdgcn_mfma_f32_16x16x32_bf16(
            a[1], *(const bf16x8*)(brow + 32), acc, 0, 0, 0);
        int cg = t * 16 + l16;
        float bv = bias[cg];
        float s = 0.f, q = 0.f;
#pragma unroll
        for (int r = 0; r < 4; ++r) {
            int rg = rbase + quad * 4 + r;
            float v = acc[r] + bv;
            if (rg < NN) out[(size_t)rg * 64 + cg] = v;
            else v = 0.f;
            s += v;
            q = fmaf(v, v, q);
        }
        s += __shfl_xor(s, 16, 64);
        s += __shfl_xor(s, 32, 64);
        q += __shfl_xor(q, 16, 64);
        q += __shfl_xor(q, 32, 64);
        if (quad == 0) {
            sS[wid][cg] = s;
            sQ[wid][cg] = q;
        }
    }
    __syncthreads();
    int c = threadIdx.x;
    if (c < 64) {
        float s = sS[0][c] + sS[1][c] + sS[2][c] + sS[3][c];
        float q = sQ[0][c] + sQ[1][c] + sQ[2][c] + sQ[3][c];
        stpart[(size_t)blockIdx.x * 128 + c] = s;
        stpart[(size_t)blockIdx.x * 128 + 64 + c] = q;
    }
}

// ============================================================================
// Vector node GEMM (kept only for the tiny ro-projection head).
// ============================================================================
template <int COUT, int CPW, int K, int IS, int OS, int MT, bool BNF, bool BOUT>
__global__ __launch_bounds__(256) void gemm_k(const float* __restrict__ in,
                                              const float* __restrict__ wT,
                                              const float* __restrict__ bias,
                                              const float* __restrict__ st,
                                              float* __restrict__ out) {
    constexpr int CP = 4 * CPW;
    constexpr int RM = MT / 64;
    constexpr int XR = MT + 1;
    __shared__ __align__(16) float xs[K * XR];
    __shared__ __align__(16) float wsh[K * CP];
    int base = blockIdx.x * MT;
    for (int p = threadIdx.x; p < K * CP / 4; p += 256)
        ((float4*)wsh)[p] = ((const float4*)wT)[p];
    for (int p = threadIdx.x; p < MT * K; p += 256) {
        int n = p / K, j = p - n * K;
        float v = (base + n < NN) ? in[(size_t)(base + n) * IS + j] : 0.f;
        if constexpr (BNF) v = fmaxf(fmaf(v, st[128 + j], st[192 + j]), 0.f);
        xs[j * XR + n] = v;
    }
    __syncthreads();
    int wid = __builtin_amdgcn_readfirstlane(threadIdx.x >> 6);
    int lane = threadIdx.x & 63;
    int c0 = wid * CPW;
    if (c0 >= COUT) return;
    float acc[RM][CPW];
#pragma unroll
    for (int k = 0; k < CPW; ++k) {
        float bv = (c0 + k < COUT) ? bias[c0 + k] : 0.f;
#pragma unroll
        for (int r = 0; r < RM; ++r) acc[r][k] = bv;
    }
    for (int j = 0; j < K; ++j) {
        float a[RM];
#pragma unroll
        for (int r = 0; r < RM; ++r) a[r] = xs[j * XR + 64 * r + lane];
#pragma unroll
        for (int q = 0; q < CPW / 4; ++q) {
            float4 wv = *(const float4*)&wsh[j * CP + c0 + 4 * q];
#pragma unroll
            for (int r = 0; r < RM; ++r) {
                acc[r][4 * q + 0] = fmaf(a[r], wv.x, acc[r][4 * q + 0]);
                acc[r][4 * q + 1] = fmaf(a[r], wv.y, acc[r][4 * q + 1]);
                acc[r][4 * q + 2] = fmaf(a[r], wv.z, acc[r][4 * q + 2]);
                acc[r][4 * q + 3] = fmaf(a[r], wv.w, acc[r][4 * q + 3]);
            }
        }
    }
#pragma unroll
    for (int r = 0; r < RM; ++r) {
        int node = base + 64 * r + lane;
        if (node < NN) {
#pragma unroll
            for (int k = 0; k < CPW; ++k) {
                if (c0 + k < COUT) {
                    if constexpr (BOUT) {
                        __hip_bfloat16* ob = (__hip_bfloat16*)out;
                        ob[(size_t)node * OS + c0 + k] = __float2bfloat16(acc[r][k]);
                    } else {
                        out[(size_t)node * OS + c0 + k] = acc[r][k];
                    }
                }
            }
        }
    }
}

// ============================================================================
// MFMA final cls GEMM (unchanged).
// ============================================================================
__global__ __launch_bounds__(256) void mfma_cls_k(
    const unsigned short* __restrict__ aggc16,
    const unsigned short* __restrict__ wcg16,
    const float* __restrict__ bgc,
    float* __restrict__ out) {
    int wid = __builtin_amdgcn_readfirstlane(threadIdx.x >> 6);
    int lane = threadIdx.x & 63;
    int quad = lane >> 4;
    int l16 = lane & 15;
    int mbase = blockIdx.x * 64 + wid * 16;
    bf16x8 a[4];
    const unsigned short* arow = aggc16 + (size_t)(mbase + l16) * 128 + quad * 8;
#pragma unroll
    for (int kc = 0; kc < 4; ++kc)
        a[kc] = *(const bf16x8*)(arow + kc * 32);
    for (int t = 0; t < 7; ++t) {
        const unsigned short* brow = wcg16 + t * 2048 + l16 * 128 + quad * 8;
        f32x4 acc = {0.f, 0.f, 0.f, 0.f};
#pragma unroll
        for (int kc = 0; kc < 4; ++kc) {
            bf16x8 b = *(const bf16x8*)(brow + kc * 32);
            acc = __builtin_amdgcn_mfma_f32_16x16x32_bf16(a[kc], b, acc, 0, 0, 0);
        }
        int cg = t * 16 + l16;
        if (cg < NCLS) {
            float bv = bgc[cg];
#pragma unroll
            for (int r = 0; r < 4; ++r) {
                int rg = mbase + quad * 4 + r;
                if (rg < NN) out[(size_t)rg * NCLS + cg] = acc[r] + bv;
            }
        }
    }
}

// reduce per-block partials -> BN scale/shift. 1024 threads, 16-way split.
__global__ __launch_bounds__(1024) void bnpar_k(const float* __restrict__ stpart,
                                                const float* __restrict__ g,
                                                const float* __restrict__ b,
                                                float* __restrict__ st, int nparts) {
    __shared__ float sS[16][64], sQ[16][64];
    int c = threadIdx.x & 63;
    int part = threadIdx.x >> 6;
    float s = 0.f, q = 0.f;
    for (int i = part; i < nparts; i += 16) {
        s += stpart[(size_t)i * 128 + c];
        q += stpart[(size_t)i * 128 + 64 + c];
    }
    sS[part][c] = s;
    sQ[part][c] = q;
    __syncthreads();
    if (part == 0) {
        s = 0.f; q = 0.f;
#pragma unroll
        for (int w = 0; w < 16; ++w) { s += sS[w][c]; q += sQ[w][c]; }
        float mu = s * (1.0f / NN);
        float var = q * (1.0f / NN) - mu * mu;
        float sc = g[c] * rsqrtf(var + EPS_BN);
        st[128 + c] = sc;
        st[192 + c] = b[c] - mu * sc;
    }
}

// ============================================================================
// Edge segment-max over CSR, bf16 payloads. Per-lane dx/dy precomputed at
// batch staging (wave-identical subtraction hoisted out of the j-loop).
// ============================================================================
__global__ __launch_bounds__(256) void edge1_k(const unsigned short* __restrict__ y,  // bf16, stride 64
                                               const float2* __restrict__ pos2,
                                               const int* __restrict__ rs,
                                               const int* __restrict__ csrc,
                                               const float* __restrict__ wl,  // (64,66)
                                               float* __restrict__ agg) {
    int wid = __builtin_amdgcn_readfirstlane(threadIdx.x >> 6);
    int lane = threadIdx.x & 63;
    int node = blockIdx.x * 4 + wid;
    if (node >= NN) return;
    float wp0 = wl[lane * 66 + 64], wp1 = wl[lane * 66 + 65];
    float2 pd = pos2[node];
    int i0 = rs[node], i1 = rs[node + 1];
    float acc = NINF;
    for (int ib = i0; ib < i1; ib += 64) {
        int m = i1 - ib;
        if (m > 64) m = 64;
        int t = ib + lane;
        int idx = (t < i1) ? csrc[t] : 0;
        float2 pp = pos2[idx];
        float dxl = pp.x - pd.x, dyl = pp.y - pd.y;
        int j = 0;
        for (; j + 8 <= m; j += 8) {
            float v[8];
#pragma unroll
            for (int q = 0; q < 8; ++q)
                v[q] = b2f(y[(size_t)rl_i(idx, j + q) * 64 + lane]);
#pragma unroll
            for (int q = 0; q < 8; ++q)
                acc = fmaxf(acc, fmaf(rl_f(dyl, j + q), wp1,
                                      fmaf(rl_f(dxl, j + q), wp0, v[q])));
        }
        for (; j < m; ++j) {
            float v = b2f(y[(size_t)rl_i(idx, j) * 64 + lane]);
            acc = fmaxf(acc, fmaf(rl_f(dyl, j), wp1, fmaf(rl_f(dxl, j), wp0, v)));
        }
    }
    agg[(size_t)node * 64 + lane] = fmaxf(acc, 0.0f);
}

// y12: bf16 [n][64]{c1,c2} pairs -> one uint per lane
__global__ __launch_bounds__(256) void edge2_k(const unsigned* __restrict__ y12,
                                               const float2* __restrict__ pos2,
                                               const int* __restrict__ rs,
                                               const int* __restrict__ csrc,
                                               const float* __restrict__ wlA,
                                               const float* __restrict__ wlB,
                                               float* __restrict__ a1,
                                               float* __restrict__ a2) {
    int wid = __builtin_amdgcn_readfirstlane(threadIdx.x >> 6);
    int lane = threadIdx.x & 63;
    int node = blockIdx.x * 4 + wid;
    if (node >= NN) return;
    float wa0 = wlA[lane * 66 + 64], wa1 = wlA[lane * 66 + 65];
    float wb0 = wlB[lane * 66 + 64], wb1 = wlB[lane * 66 + 65];
    float2 pd = pos2[node];
    int i0 = rs[node], i1 = rs[node + 1];
    float accA = NINF, accB = NINF;
    for (int ib = i0; ib < i1; ib += 64) {
        int m = i1 - ib;
        if (m > 64) m = 64;
        int t = ib + lane;
        int idx = (t < i1) ? csrc[t] : 0;
        float2 pp = pos2[idx];
        float dxl = pp.x - pd.x, dyl = pp.y - pd.y;
        int j = 0;
        for (; j + 8 <= m; j += 8) {
            unsigned w[8];
#pragma unroll
            for (int q = 0; q < 8; ++q)
                w[q] = y12[(size_t)rl_i(idx, j + q) * 64 + lane];
#pragma unroll
            for (int q = 0; q < 8; ++q) {
                float dx = rl_f(dxl, j + q), dy = rl_f(dyl, j + q);
                accA = fmaxf(accA, fmaf(dy, wa1, fmaf(dx, wa0,
                                        b2f((unsigned short)w[q]))));
                accB = fmaxf(accB, fmaf(dy, wb1, fmaf(dx, wb0,
                                        b2f((unsigned short)(w[q] >> 16)))));
            }
        }
        for (; j < m; ++j) {
            unsigned w = y12[(size_t)rl_i(idx, j) * 64 + lane];
            float dx = rl_f(dxl, j), dy = rl_f(dyl, j);
            accA = fmaxf(accA, fmaf(dy, wa1, fmaf(dx, wa0, b2f((unsigned short)w))));
            accB = fmaxf(accB, fmaf(dy, wb1, fmaf(dx, wb0,
                                    b2f((unsigned short)(w >> 16)))));
        }
    }
    a1[(size_t)node * 64 + lane] = fmaxf(accA, 0.0f);
    a2[(size_t)node * 64 + lane] = fmaxf(accB, 0.0f);
}

// Merged cls+reg+obj edge pass: wave per node; loop 1 = cls (interleaved
// dword gathers -> aggb bf16 [n][128]); loop 2 = reg/obj (5 bf16 channels).
__global__ __launch_bounds__(256) void edge_clsro_k(
    const unsigned* __restrict__ y32,        // interleaved cls proj, stride 64
    const unsigned short* __restrict__ yro,  // bf16, stride 8
    const float2* __restrict__ pos2,
    const int* __restrict__ rs,
    const int* __restrict__ csrc,
    const float* __restrict__ wl,            // (101,66)
    const float* __restrict__ wro,           // (5,66)
    unsigned short* __restrict__ aggb,
    float* __restrict__ aggr,
    float* __restrict__ aggo) {
    int wid = __builtin_amdgcn_readfirstlane(threadIdx.x >> 6);
    int lane = threadIdx.x & 63;
    int node = blockIdx.x * 4 + wid;
    if (node >= NN) return;
    int chi = (lane + 64 < NCLS) ? (lane + 64) : (NCLS - 1);
    float wa0 = wl[lane * 66 + 64], wa1 = wl[lane * 66 + 65];
    float wb0 = wl[chi * 66 + 64], wb1 = wl[chi * 66 + 65];
    float2 pd = pos2[node];
    int i0 = rs[node], i1 = rs[node + 1];
    float accA = NINF, accB = NINF;
    for (int ib = i0; ib < i1; ib += 64) {
        int m = i1 - ib;
        if (m > 64) m = 64;
        int t = ib + lane;
        int idx = (t < i1) ? csrc[t] : 0;
        float2 pp = pos2[idx];
        float dxl = pp.x - pd.x, dyl = pp.y - pd.y;
        int j = 0;
        for (; j + 8 <= m; j += 8) {
            unsigned w[8];
#pragma unroll
            for (int q = 0; q < 8; ++q)
                w[q] = y32[(size_t)rl_i(idx, j + q) * 64 + lane];
#pragma unroll
            for (int q = 0; q < 8; ++q) {
                float dx = rl_f(dxl, j + q), dy = rl_f(dyl, j + q);
                accA = fmaxf(accA, fmaf(dy, wa1, fmaf(dx, wa0,
                                        b2f((unsigned short)w[q]))));
                accB = fmaxf(accB, fmaf(dy, wb1, fmaf(dx, wb0,
                                        b2f((unsigned short)(w[q] >> 16)))));
            }
        }
        for (; j < m; ++j) {
            unsigned w = y32[(size_t)rl_i(idx, j) * 64 + lane];
            float dx = rl_f(dxl, j), dy = rl_f(dyl, j);
            accA = fmaxf(accA, fmaf(dy, wa1, fmaf(dx, wa0, b2f((unsigned short)w))));
            accB = fmaxf(accB, fmaf(dy, wb1, fmaf(dx, wb0,
                                    b2f((unsigned short)(w >> 16)))));
        }
    }
    aggb[(size_t)node * 128 + lane] = f2b(fmaxf(accA, 0.0f));
    unsigned short hb = (lane + 64 < NCLS) ? f2b(fmaxf(accB, 0.0f)) : (unsigned short)0;
    aggb[(size_t)node * 128 + 64 + lane] = hb;
    // ---- reg/obj loop: 8 edge-slots x 8 channel-slots ----
    int k = lane >> 3, c = lane & 7;
    int cc = (c < 5) ? c : 4;
    float wp0 = wro[cc * 66 + 64], wp1 = wro[cc * 66 + 65];
    float acc = NINF;
    for (int i = i0 + k; i < i1; i += 8) {
        int s = csrc[i];
        float2 p = pos2[s];
        float v = b2f(yro[(size_t)s * 8 + cc]);
        acc = fmaxf(acc, fmaf(p.y - pd.y, wp1, fmaf(p.x - pd.x, wp0, v)));
    }
    acc = fmaxf(acc, __shfl_xor(acc, 8, 64));
    acc = fmaxf(acc, __shfl_xor(acc, 16, 64));
    acc = fmaxf(acc, __shfl_xor(acc, 32, 64));
    acc = fmaxf(acc, 0.0f);
    if (lane < 5) {
        if (lane < 4) aggr[(size_t)node * 4 + lane] = acc;
        else          aggo[node] = acc;
    }
}

__global__ __launch_bounds__(256) void final_ro_k(const float* __restrict__ aggr,
                                                  const float* __restrict__ aggo,
                                                  const float* __restrict__ wgr,
                                                  const float* __restrict__ bgr,
                                                  const float* __restrict__ wgo,
                                                  const float* __restrict__ bgo,
                                                  float* __restrict__ out) {
    int n = blockIdx.x * 256 + threadIdx.x;
    if (n >= NN) return;
    float a0 = aggr[(size_t)n * 4 + 0], a1 = aggr[(size_t)n * 4 + 1];
    float a2 = aggr[(size_t)n * 4 + 2], a3 = aggr[(size_t)n * 4 + 3];
    float* reg = out + (size_t)NN * NCLS;
    float* obj = reg + (size_t)NN * 4;
#pragma unroll
    for (int k = 0; k < 4; ++k) {
        float acc = bgr[k];
        acc = fmaf(a0, wgr[k * 4 + 0], acc);
        acc = fmaf(a1, wgr[k * 4 + 1], acc);
        acc = fmaf(a2, wgr[k * 4 + 2], acc);
        acc = fmaf(a3, wgr[k * 4 + 3], acc);
        reg[(size_t)n * 4 + k] = acc;
    }
    obj[n] = fmaf(aggo[n], wgo[0], bgo[0]);
}

// ============================================================================
extern "C" void kernel_launch(void* const* d_in, const int* in_sizes, int n_in,
                              void* d_out, int out_size, void* d_ws, size_t ws_size,
                              hipStream_t stream) {
    const float* x   = (const float*)d_in[0];
    const float* pos = (const float*)d_in[1];
    const int* ei    = (const int*)d_in[2];
    const int* src = ei;
    const int* dst = ei + NE;
    const float* wl_stem = (const float*)d_in[3];
    const float* bl_stem = (const float*)d_in[4];
    const float* wg_stem = (const float*)d_in[5];
    const float* bg_stem = (const float*)d_in[6];
    const float* g_stem  = (const float*)d_in[7];
    const float* b_stem  = (const float*)d_in[8];
    const float* wl_c1 = (const float*)d_in[9];
    const float* bl_c1 = (const float*)d_in[10];
    const float* wg_c1 = (const float*)d_in[11];
    const float* bg_c1 = (const float*)d_in[12];
    const float* g_c1  = (const float*)d_in[13];
    const float* b_c1  = (const float*)d_in[14];
    const float* wl_c2 = (const float*)d_in[15];
    const float* bl_c2 = (const float*)d_in[16];
    const float* wg_c2 = (const float*)d_in[17];
    const float* bg_c2 = (const float*)d_in[18];
    const float* g_c2  = (const float*)d_in[19];
    const float* b_c2  = (const float*)d_in[20];
    const float* wl_reg = (const float*)d_in[21];
    const float* bl_reg = (const float*)d_in[22];
    const float* wg_reg = (const float*)d_in[23];
    const float* bg_reg = (const float*)d_in[24];
    const float* wl_cls = (const float*)d_in[25];
    const float* bl_cls = (const float*)d_in[26];
    const float* wg_cls = (const float*)d_in[27];
    const float* bg_cls = (const float*)d_in[28];
    const float* wl_obj = (const float*)d_in[29];
    const float* bl_obj = (const float*)d_in[30];
    const float* wg_obj = (const float*)d_in[31];
    const float* bg_obj = (const float*)d_in[32];

    float* ws = (float*)d_ws;
    // Arena: S0[N*128] | S1[N*64] | S2[N*64] | S3[N*64] | ints/smalls
    float* S0 = ws;
    float* S1 = S0 + (size_t)NN * 128;
    float* S2 = S1 + (size_t)NN * 64;
    float* S3 = S2 + (size_t)NN * 64;
    float* y12   = S0;       // bf16 [n][128]
    float* y_cls = S0;       // bf16 [n][128] interleaved dwords
    unsigned short* aggc16 = (unsigned short*)S1;   // bf16 [n][128]
    int*   bstore = (int*)S0;                     // NBUCK*BCAP ints
    int*   rs   = (int*)(S3 + (size_t)NN * 64);   // NN+1 (padded)
    int*   csrc = rs + 100016;                    // NE
    float* pos2 = (float*)(csrc + NE);            // NN float2
    float* y_ro = pos2 + (size_t)NN * 2;          // bf16 [n][8] (fp32-sized slot)
    float* aggr = y_ro + (size_t)NN * 8;          // NN*4
    float* aggo = aggr + (size_t)NN * 4;          // NN
    float* st   = aggo + NN;                      // 3*256 (params at [128..255])
    float* st0 = st, *st1 = st + 256, *st2 = st + 512;
    float* wro = st + 768;                        // 336
    float* bro = wro + 336;                       // 16
    int*   bcnt16 = (int*)(bro + 16);             // NBUCK*16
    int*   bbase  = bcnt16 + NBUCK * 16;          // 256
    float* wT_ro = (float*)(bbase + 256);         // [64][16] fp32
    unsigned short* wb_sg = (unsigned short*)(wT_ro + 1024);  // 4096
    unsigned short* wb_g1 = wb_sg + 4096;                     // 4096
    unsigned short* wb_g2 = wb_g1 + 4096;                     // 4096
    unsigned short* wb_sp = wb_g2 + 4096;                     // 4096
    unsigned short* wb_12 = wb_sp + 4096;                     // 8192
    unsigned short* wb_cp = wb_12 + 8192;                     // 8192
    unsigned short* wcg16 = wb_cp + 8192;                     // 14336
    float* bAB   = (float*)(wcg16 + 14336);       // 128
    float* stpart = bAB + 128;                    // MBK*128 floats (~800 KB)

    hipMemsetAsync(bcnt16, 0, NBUCK * 16 * sizeof(int), stream);

    const int NB = (NN + 255) / 256;      // 391
    const int N4 = (NN + 3) / 4;          // 25000
    const int CB = (NE + CHUNK - 1) / CHUNK;  // 782

    // ---- packing + CSR build + pos2 ----
    pack_all_k<<<190, 256, 0, stream>>>(wl_stem, wg_stem, wl_c1, bl_c1, wl_c2,
                                        bl_c2, wg_c1, wg_c2, wl_reg, wl_obj,
                                        bl_reg, bl_obj, wl_cls, wg_cls,
                                        wT_ro, wb_sg, wb_g1, wb_g2, wb_sp,
                                        wb_12, wb_cp, wcg16, bAB, wro, bro);
    pos2_k<<<NB, 256, 0, stream>>>(pos, (float2*)pos2);
    bucket_k<<<CB, 256, 0, stream>>>(src, dst, bcnt16, bstore);
    bscan_k<<<1, 256, 0, stream>>>(bcnt16, bbase);
    b2csr_k<<<NBUCK, 512, 0, stream>>>(bcnt16, bbase, bstore, rs, csrc);

    // ---- stem ----
    mfma_lin_k<64, 64, 64, 64, false, false><<<MBK, 256, 0, stream>>>(
        x, wb_sp, bl_stem, nullptr, (unsigned short*)S1);   // y_stem bf16
    edge1_k<<<N4, 256, 0, stream>>>((const unsigned short*)S1, (float2*)pos2, rs,
                                    csrc, wl_stem, S2);
    mfma_stats_k<<<MBK, 256, 0, stream>>>(S2, wb_sg, bg_stem, S2, stpart);
    bnpar_k<<<1, 1024, 0, stream>>>(stpart, g_stem, b_stem, st0, MBK);

    // ---- c1 + c2 (BN fused into packed MFMA projection, shared edge pass) ----
    mfma_lin_k<128, 128, 64, 128, true, false><<<MBK, 256, 0, stream>>>(
        S2, wb_12, bAB, st0, (unsigned short*)y12);         // y12 bf16 pairs
    edge2_k<<<N4, 256, 0, stream>>>((const unsigned*)y12, (float2*)pos2, rs, csrc,
                                    wl_c1, wl_c2, S1, S3);
    mfma_stats_k<<<MBK, 256, 0, stream>>>(S1, wb_g1, bg_c1, S1, stpart);
    bnpar_k<<<1, 1024, 0, stream>>>(stpart, g_c1, b_c1, st1, MBK);
    mfma_stats_k<<<MBK, 256, 0, stream>>>(S3, wb_g2, bg_c2, S3, stpart);
    bnpar_k<<<1, 1024, 0, stream>>>(stpart, g_c2, b_c2, st2, MBK);

    // ---- reg + obj projection (input x1 = BN(S1), fused) ----
    gemm_k<5, 4, 64, 64, 8, 192, true, true><<<G192B, 256, 0, stream>>>(
        S1, wT_ro, bro, st1, y_ro);                         // y_ro bf16
    // ---- cls projection (input x2 = BN(S3), fused; interleaved y_cls) ----
    mfma_lin_k<128, NCLS, 64, 128, true, true><<<MBK, 256, 0, stream>>>(
        S3, wb_cp, bl_cls, st2, (unsigned short*)y_cls);

    // ---- merged cls + reg/obj edge pass ----
    edge_clsro_k<<<N4, 256, 0, stream>>>((const unsigned*)y_cls,
                                         (const unsigned short*)y_ro,
                                         (float2*)pos2, rs, csrc, wl_cls, wro,
                                         aggc16, aggr, aggo);

    mfma_cls_k<<<MBK, 256, 0, stream>>>(aggc16, wcg16, bg_cls, (float*)d_out);
    final_ro_k<<<NB, 256, 0, stream>>>(aggr, aggo, wg_reg, bg_reg, wg_obj, bg_obj,
                                       (float*)d_out);
}